// Round 1
// baseline (2455.714 us; speedup 1.0000x reference)
//
#include <hip/hip_runtime.h>

#define FDIM 320
#define NHEADS 10
#define NGR 256

typedef __bf16 bf16x8 __attribute__((ext_vector_type(8)));
typedef float f32x4 __attribute__((ext_vector_type(4)));

// ---------------- GEMM: C[M,N] = A[M,K] (f32) * B[K,N] (f32), bf16 MFMA ----
#define BM 128
#define BN 64
#define BK 32
#define LSTR 56   // LDS row stride in elems: 112B, 16B-aligned, 2-way bank alias only

template<int FLAGS>  // bit0: relu, bit1: bias
__global__ __launch_bounds__(256) void gemm_bf16_kernel(
    const float* __restrict__ A, const float* __restrict__ B,
    float* __restrict__ C, const float* __restrict__ bias,
    int M, int N, int K, int ldc)
{
  __shared__ __bf16 As[BM * LSTR];
  __shared__ __bf16 Bs[BN * LSTR];

  const int tid = threadIdx.x;
  const int lane = tid & 63;
  const int w = tid >> 6;
  const int wm = w >> 1, wn = w & 1;     // 2x2 waves, each 64x32 out
  const int r = lane & 15, kg = lane >> 4;
  const int m0 = blockIdx.x * BM, n0 = blockIdx.y * BN;

  f32x4 acc[4][2];
  #pragma unroll
  for (int i = 0; i < 4; i++)
    #pragma unroll
    for (int j = 0; j < 2; j++)
      acc[i][j] = (f32x4){0.f, 0.f, 0.f, 0.f};

  const int arow = tid >> 1, ahalf = tid & 1;     // A stage: 16 f32/thread
  const int bk = tid >> 3, bn = (tid & 7) * 8;    // B stage: 8 f32/thread

  for (int k0 = 0; k0 < K; k0 += BK) {
    __syncthreads();
    // ---- stage A tile [BM x BK] ----
    {
      int gm = m0 + arow;
      int kbase = k0 + ahalf * 16;
      float tmp[16];
      if (gm < M && kbase + 16 <= K) {
        const float4* ap = (const float4*)(A + (size_t)gm * K + kbase);
        #pragma unroll
        for (int q = 0; q < 4; q++) {
          float4 v = ap[q];
          tmp[q*4+0] = v.x; tmp[q*4+1] = v.y; tmp[q*4+2] = v.z; tmp[q*4+3] = v.w;
        }
      } else {
        #pragma unroll
        for (int q = 0; q < 16; q++) {
          int kk = kbase + q;
          tmp[q] = (gm < M && kk < K) ? A[(size_t)gm * K + kk] : 0.f;
        }
      }
      bf16x8 v0, v1;
      #pragma unroll
      for (int q = 0; q < 8; q++) { v0[q] = (__bf16)tmp[q]; v1[q] = (__bf16)tmp[q+8]; }
      bf16x8* dp = (bf16x8*)&As[arow * LSTR + ahalf * 16];
      dp[0] = v0; dp[1] = v1;
    }
    // ---- stage B tile transposed: Bs[n][k] = B[k0+k][n0+n] ----
    {
      int gk = k0 + bk;
      float tb[8];
      if (gk < K && n0 + bn + 8 <= N) {
        const float4* bp = (const float4*)(B + (size_t)gk * N + n0 + bn);
        float4 u0 = bp[0], u1 = bp[1];
        tb[0]=u0.x; tb[1]=u0.y; tb[2]=u0.z; tb[3]=u0.w;
        tb[4]=u1.x; tb[5]=u1.y; tb[6]=u1.z; tb[7]=u1.w;
      } else {
        #pragma unroll
        for (int q = 0; q < 8; q++) {
          int gn = n0 + bn + q;
          tb[q] = (gk < K && gn < N) ? B[(size_t)gk * N + gn] : 0.f;
        }
      }
      #pragma unroll
      for (int q = 0; q < 8; q++) Bs[(bn + q) * LSTR + bk] = (__bf16)tb[q];
    }
    __syncthreads();
    // ---- compute ----
    bf16x8 af[4], bfr[2];
    #pragma unroll
    for (int mf = 0; mf < 4; mf++)
      af[mf] = *(const bf16x8*)&As[(wm*64 + mf*16 + r) * LSTR + kg*8];
    #pragma unroll
    for (int nf = 0; nf < 2; nf++)
      bfr[nf] = *(const bf16x8*)&Bs[(wn*32 + nf*16 + r) * LSTR + kg*8];
    #pragma unroll
    for (int mf = 0; mf < 4; mf++)
      #pragma unroll
      for (int nf = 0; nf < 2; nf++)
        acc[mf][nf] = __builtin_amdgcn_mfma_f32_16x16x32_bf16(af[mf], bfr[nf], acc[mf][nf], 0, 0, 0);
  }

  // ---- epilogue ----
  #pragma unroll
  for (int mf = 0; mf < 4; mf++) {
    #pragma unroll
    for (int nf = 0; nf < 2; nf++) {
      #pragma unroll
      for (int q = 0; q < 4; q++) {
        int gm = m0 + wm*64 + mf*16 + kg*4 + q;
        int gn = n0 + wn*32 + nf*16 + r;
        if (gm < M && gn < N) {
          float v = acc[mf][nf][q];
          if (FLAGS & 2) v += bias[gn];
          if (FLAGS & 1) v = fmaxf(v, 0.f);
          C[(size_t)gm * ldc + gn] = v;
        }
      }
    }
  }
}

// ---------------- CSR build ----------------
__global__ void count_kernel(const int* __restrict__ dst, int* __restrict__ cnt, int E) {
  int e = blockIdx.x * 256 + threadIdx.x;
  if (e < E) atomicAdd(&cnt[dst[e]], 1);
}

__global__ void scan_kernel(const int* __restrict__ cnt, int* __restrict__ rp, int n) {
  __shared__ int wpart[4];
  __shared__ int carry_s, btot;
  int tid = threadIdx.x;
  int lane = tid & 63, wid = tid >> 6;
  if (tid == 0) carry_s = 0;
  __syncthreads();
  for (int base = 0; base < n; base += 256) {
    int i = base + tid;
    int v = (i < n) ? cnt[i] : 0;
    int xv = v;
    #pragma unroll
    for (int off2 = 1; off2 < 64; off2 <<= 1) {
      int y = __shfl_up(xv, off2, 64);
      if (lane >= off2) xv += y;
    }
    if (lane == 63) wpart[wid] = xv;
    __syncthreads();
    if (tid == 0) {
      int s = 0;
      #pragma unroll
      for (int k = 0; k < 4; k++) { int t2 = wpart[k]; wpart[k] = s; s += t2; }
      btot = s;
    }
    __syncthreads();
    if (i < n) rp[i] = carry_s + wpart[wid] + xv - v;
    __syncthreads();
    if (tid == 0) carry_s += btot;
    __syncthreads();
  }
  if (tid == 0) rp[n] = carry_s;
}

__global__ void dinv_kernel(const int* __restrict__ cnt, float* __restrict__ dinv, int n) {
  int v = blockIdx.x * 256 + threadIdx.x;
  if (v < n) dinv[v] = rsqrtf((float)(cnt[v] + 1));
}

__global__ void fill_kernel(const int* __restrict__ src, const int* __restrict__ dst,
                            const int* __restrict__ rp, int* __restrict__ fil,
                            int* __restrict__ csr, int E) {
  int e = blockIdx.x * 256 + threadIdx.x;
  if (e < E) {
    int d = dst[e];
    int pos = rp[d] + atomicAdd(&fil[d], 1);
    csr[pos] = src[e];
  }
}

// ---------------- GCN aggregate (one wave per node) ----------------
__global__ void gcn_agg_kernel(const float* __restrict__ h, const int* __restrict__ rp,
                               const int* __restrict__ csr, const float* __restrict__ dinv,
                               const float* __restrict__ bias, float* __restrict__ out, int n)
{
  const int lane = threadIdx.x & 63;
  const int v = blockIdx.x * 4 + (threadIdx.x >> 6);
  if (v >= n) return;
  const float dv = dinv[v];
  const int e0 = rp[v], e1 = rp[v + 1];
  float acc[5];
  #pragma unroll
  for (int j = 0; j < 5; j++) acc[j] = dv * h[(size_t)v * FDIM + lane + 64 * j];
  for (int e = e0; e < e1; e++) {
    int s = csr[e];
    float ds = dinv[s];
    const float* hs = h + (size_t)s * FDIM;
    #pragma unroll
    for (int j = 0; j < 5; j++) acc[j] += ds * hs[lane + 64 * j];
  }
  #pragma unroll
  for (int j = 0; j < 5; j++) {
    float rr = dv * acc[j] + bias[lane + 64 * j];
    out[(size_t)v * FDIM + lane + 64 * j] = fmaxf(rr, 0.f);
  }
}

// ---------------- GAT attention scores a_s, a_d (one wave per node) --------
__global__ void gat_scores_kernel(const float* __restrict__ h, const float* __restrict__ att_s,
                                  const float* __restrict__ att_d, float* __restrict__ as_,
                                  float* __restrict__ ad_, int n)
{
  const int lane = threadIdx.x & 63;
  const int v = blockIdx.x * 4 + (threadIdx.x >> 6);
  if (v >= n) return;
  const int c = lane & 31;
  const int hh = lane >> 5;
  #pragma unroll
  for (int j = 0; j < 5; j++) {
    int head = hh * 5 + j;
    float xv = h[(size_t)v * FDIM + head * 32 + c];
    float ps = xv * att_s[head * 32 + c];
    float pd = xv * att_d[head * 32 + c];
    #pragma unroll
    for (int off = 1; off < 32; off <<= 1) {
      ps += __shfl_xor(ps, off, 64);
      pd += __shfl_xor(pd, off, 64);
    }
    if (c == 0) { as_[v * NHEADS + head] = ps; ad_[v * NHEADS + head] = pd; }
  }
}

__device__ __forceinline__ float lrelu(float x) { return x > 0.f ? x : 0.2f * x; }

// ---------------- GAT aggregate (one wave per node, 2 passes) --------------
__global__ void gat_agg_kernel(const float* __restrict__ h, const int* __restrict__ rp,
                               const int* __restrict__ csr, const float* __restrict__ as_,
                               const float* __restrict__ ad_, const float* __restrict__ bias,
                               float* __restrict__ out, int n)
{
  const int lane = threadIdx.x & 63;
  const int v = blockIdx.x * 4 + (threadIdx.x >> 6);
  if (v >= n) return;
  const int hb = lane >> 5;          // head parity selector for this lane's channels
  const int e0 = rp[v], e1 = rp[v + 1];
  float adv[NHEADS], es[NHEADS], m[NHEADS];
  #pragma unroll
  for (int t = 0; t < NHEADS; t++) adv[t] = ad_[v * NHEADS + t];
  #pragma unroll
  for (int t = 0; t < NHEADS; t++) {
    es[t] = lrelu(as_[v * NHEADS + t] + adv[t]);
    m[t] = es[t];
  }
  // pass 1: segment max (incl. self-loop)
  for (int e = e0; e < e1; e++) {
    int s = csr[e];
    #pragma unroll
    for (int t = 0; t < NHEADS; t++)
      m[t] = fmaxf(m[t], lrelu(as_[s * NHEADS + t] + adv[t]));
  }
  // pass 2: denom + weighted sum
  float denom[NHEADS];
  float acc[5];
  {
    float p[NHEADS];
    #pragma unroll
    for (int t = 0; t < NHEADS; t++) { p[t] = __expf(es[t] - m[t]); denom[t] = p[t]; }
    #pragma unroll
    for (int j = 0; j < 5; j++) {
      float pj = (hb == 0) ? p[2 * j] : p[2 * j + 1];  // head of channel lane+64j = (lane>>5)+2j
      acc[j] = pj * h[(size_t)v * FDIM + lane + 64 * j];
    }
  }
  for (int e = e0; e < e1; e++) {
    int s = csr[e];
    float p[NHEADS];
    #pragma unroll
    for (int t = 0; t < NHEADS; t++) {
      p[t] = __expf(lrelu(as_[s * NHEADS + t] + adv[t]) - m[t]);
      denom[t] += p[t];
    }
    const float* hs = h + (size_t)s * FDIM;
    #pragma unroll
    for (int j = 0; j < 5; j++) {
      float pj = (hb == 0) ? p[2 * j] : p[2 * j + 1];
      acc[j] += pj * hs[lane + 64 * j];
    }
  }
  #pragma unroll
  for (int j = 0; j < 5; j++) {
    float dj = (hb == 0) ? denom[2 * j] : denom[2 * j + 1];
    int c = lane + 64 * j;
    float rr = acc[j] / dj + bias[c];
    out[(size_t)v * FDIM + c] = fmaxf(rr, 0.f);
  }
}

// ---------------- batch boundaries + pooling ----------------
__global__ void bstart_kernel(const int* __restrict__ batch, int* __restrict__ bstart,
                              int n, int B_) {
  int v = blockIdx.x * 256 + threadIdx.x;
  if (v > n) return;
  int bv = (v < n) ? batch[v] : B_;
  int bp = (v == 0) ? -1 : batch[v - 1];
  for (int gg = bp + 1; gg <= bv; gg++) bstart[gg] = v;
}

__global__ void pool_kernel(const float* __restrict__ xin, const int* __restrict__ bstart,
                            float* __restrict__ g) {
  int gid = blockIdx.x;
  int c = threadIdx.x;  // 320 threads
  int s = bstart[gid], e = bstart[gid + 1];
  float mx = -__builtin_inff(), sm = 0.f;
  for (int v = s; v < e; v++) {
    float val = xin[(size_t)v * FDIM + c];
    mx = fmaxf(mx, val);
    sm += val;
  }
  float cntf = (float)(e - s);
  g[gid * (2 * FDIM) + c] = mx;
  g[gid * (2 * FDIM) + FDIM + c] = sm / fmaxf(cntf, 1.f);
}

// ---------------- launch ----------------
extern "C" void kernel_launch(void* const* d_in, const int* in_sizes, int n_in,
                              void* d_out, int out_size, void* d_ws, size_t ws_size,
                              hipStream_t stream)
{
  const int N = in_sizes[0] / FDIM;
  const int E = in_sizes[2] / 2;

  const float* x[2]   = {(const float*)d_in[0], (const float*)d_in[1]};
  const int*   ei[2]  = {(const int*)d_in[2], (const int*)d_in[3]};
  const int*   bat[2] = {(const int*)d_in[4], (const int*)d_in[5]};
  const float* W_gcn   = (const float*)d_in[6];
  const float* b_gcn   = (const float*)d_in[7];
  const float* W_gat   = (const float*)d_in[8];
  const float* att_src = (const float*)d_in[9];
  const float* att_dst = (const float*)d_in[10];
  const float* b_gat   = (const float*)d_in[11];
  const float* W_fc_g1 = (const float*)d_in[12];
  const float* b_fc_g1 = (const float*)d_in[13];
  const float* W_fc_g2 = (const float*)d_in[14];
  const float* b_fc_g2 = (const float*)d_in[15];
  const float* W_fc1   = (const float*)d_in[16];
  const float* b_fc1   = (const float*)d_in[17];
  const float* W_fc2   = (const float*)d_in[18];
  const float* b_fc2   = (const float*)d_in[19];
  const float* W_out   = (const float*)d_in[20];
  const float* b_out   = (const float*)d_in[21];
  float* outp = (float*)d_out;

  char* ws = (char*)d_ws;
  size_t off = 0;
  auto alloc = [&](size_t bytes) -> char* {
    char* p = ws + off;
    off += (bytes + 255) & ~(size_t)255;
    return p;
  };
  int*   cnt    = (int*)alloc((size_t)N * 4);
  int*   fil    = (int*)alloc((size_t)N * 4);
  int*   rp     = (int*)alloc((size_t)(N + 1) * 4);
  int*   csr    = (int*)alloc((size_t)E * 4);
  float* dinv   = (float*)alloc((size_t)N * 4);
  int*   bstart = (int*)alloc((size_t)(NGR + 1) * 4);
  float* hbuf   = (float*)alloc((size_t)N * FDIM * 4);
  float* xbuf   = (float*)alloc((size_t)N * FDIM * 4);
  float* as_    = (float*)alloc((size_t)N * NHEADS * 4);
  float* ad_    = (float*)alloc((size_t)N * NHEADS * 4);
  float* g      = (float*)alloc((size_t)NGR * 2 * FDIM * 4);
  float* t1     = (float*)alloc((size_t)NGR * 1500 * 4);
  float* xc     = (float*)alloc((size_t)NGR * 256 * 4);
  float* t2     = (float*)alloc((size_t)NGR * 1024 * 4);
  float* t3     = (float*)alloc((size_t)NGR * 512 * 4);
  if (off > ws_size) return;  // workspace too small: bail (visible as absmax fail)

  for (int br = 0; br < 2; br++) {
    hipMemsetAsync(cnt, 0, (size_t)N * 4, stream);
    hipMemsetAsync(fil, 0, (size_t)N * 4, stream);
    const int* srcp = ei[br];
    const int* dstp = ei[br] + E;
    count_kernel<<<(E + 255) / 256, 256, 0, stream>>>(dstp, cnt, E);
    scan_kernel<<<1, 256, 0, stream>>>(cnt, rp, N);
    dinv_kernel<<<(N + 255) / 256, 256, 0, stream>>>(cnt, dinv, N);
    fill_kernel<<<(E + 255) / 256, 256, 0, stream>>>(srcp, dstp, rp, fil, csr, E);

    dim3 gbig((N + BM - 1) / BM, (FDIM + BN - 1) / BN);
    gemm_bf16_kernel<0><<<gbig, 256, 0, stream>>>(x[br], W_gcn, hbuf, nullptr, N, FDIM, FDIM, FDIM);
    gcn_agg_kernel<<<(N + 3) / 4, 256, 0, stream>>>(hbuf, rp, csr, dinv, b_gcn, xbuf, N);
    gemm_bf16_kernel<0><<<gbig, 256, 0, stream>>>(xbuf, W_gat, hbuf, nullptr, N, FDIM, FDIM, FDIM);
    gat_scores_kernel<<<(N + 3) / 4, 256, 0, stream>>>(hbuf, att_src, att_dst, as_, ad_, N);
    gat_agg_kernel<<<(N + 3) / 4, 256, 0, stream>>>(hbuf, rp, csr, as_, ad_, b_gat, xbuf, N);

    bstart_kernel<<<(N + 256) / 256, 256, 0, stream>>>(bat[br], bstart, N, NGR);
    pool_kernel<<<NGR, FDIM, 0, stream>>>(xbuf, bstart, g);

    dim3 gfc1((NGR + BM - 1) / BM, (1500 + BN - 1) / BN);
    gemm_bf16_kernel<3><<<gfc1, 256, 0, stream>>>(g, W_fc_g1, t1, b_fc_g1, NGR, 1500, 2 * FDIM, 1500);
    dim3 gfc2((NGR + BM - 1) / BM, (128 + BN - 1) / BN);
    gemm_bf16_kernel<2><<<gfc2, 256, 0, stream>>>(t1, W_fc_g2, xc + br * 128, b_fc_g2, NGR, 128, 1500, 256);
  }

  dim3 gx1((NGR + BM - 1) / BM, (1024 + BN - 1) / BN);
  gemm_bf16_kernel<3><<<gx1, 256, 0, stream>>>(xc, W_fc1, t2, b_fc1, NGR, 1024, 256, 1024);
  dim3 gx2((NGR + BM - 1) / BM, (512 + BN - 1) / BN);
  gemm_bf16_kernel<3><<<gx2, 256, 0, stream>>>(t2, W_fc2, t3, b_fc2, NGR, 512, 1024, 512);
  dim3 gx3((NGR + BM - 1) / BM, 1);
  gemm_bf16_kernel<2><<<gx3, 256, 0, stream>>>(t3, W_out, outp, b_out, NGR, 2, 512, 2);
}

// Round 2
// 1404.294 us; speedup vs baseline: 1.7487x; 1.7487x over previous
//
#include <hip/hip_runtime.h>

#define FDIM 320
#define NHEADS 10
#define NGR 256

typedef __bf16 bf16x8 __attribute__((ext_vector_type(8)));
typedef float f32x4 __attribute__((ext_vector_type(4)));

// ---------------- GEMM: C[M,N] = A[M,K] (f32) * B[K,N] (f32), bf16 MFMA ----
#define BM 128
#define BN 64
#define BK 32
#define LSTR 56   // LDS row stride in elems: 112B, 16B-aligned, 2-way bank alias only

template<int FLAGS>  // bit0: relu, bit1: bias
__global__ __launch_bounds__(256) void gemm_bf16_kernel(
    const float* __restrict__ A, const float* __restrict__ B,
    float* __restrict__ C, const float* __restrict__ bias,
    int M, int N, int K, int ldc)
{
  __shared__ __bf16 As[BM * LSTR];
  __shared__ __bf16 Bs[BN * LSTR];

  const int tid = threadIdx.x;
  const int lane = tid & 63;
  const int w = tid >> 6;
  const int wm = w >> 1, wn = w & 1;     // 2x2 waves, each 64x32 out
  const int r = lane & 15, kg = lane >> 4;
  const int m0 = blockIdx.x * BM, n0 = blockIdx.y * BN;

  f32x4 acc[4][2];
  #pragma unroll
  for (int i = 0; i < 4; i++)
    #pragma unroll
    for (int j = 0; j < 2; j++)
      acc[i][j] = (f32x4){0.f, 0.f, 0.f, 0.f};

  const int arow = tid >> 1, ahalf = tid & 1;     // A stage: 16 f32/thread
  const int bk = tid >> 3, bn = (tid & 7) * 8;    // B stage: 8 f32/thread

  for (int k0 = 0; k0 < K; k0 += BK) {
    __syncthreads();
    // ---- stage A tile [BM x BK] ----
    {
      int gm = m0 + arow;
      int kbase = k0 + ahalf * 16;
      float tmp[16];
      if (gm < M && kbase + 16 <= K) {
        const float4* ap = (const float4*)(A + (size_t)gm * K + kbase);
        #pragma unroll
        for (int q = 0; q < 4; q++) {
          float4 v = ap[q];
          tmp[q*4+0] = v.x; tmp[q*4+1] = v.y; tmp[q*4+2] = v.z; tmp[q*4+3] = v.w;
        }
      } else {
        #pragma unroll
        for (int q = 0; q < 16; q++) {
          int kk = kbase + q;
          tmp[q] = (gm < M && kk < K) ? A[(size_t)gm * K + kk] : 0.f;
        }
      }
      bf16x8 v0, v1;
      #pragma unroll
      for (int q = 0; q < 8; q++) { v0[q] = (__bf16)tmp[q]; v1[q] = (__bf16)tmp[q+8]; }
      bf16x8* dp = (bf16x8*)&As[arow * LSTR + ahalf * 16];
      dp[0] = v0; dp[1] = v1;
    }
    // ---- stage B tile transposed: Bs[n][k] = B[k0+k][n0+n] ----
    {
      int gk = k0 + bk;
      float tb[8];
      if (gk < K && n0 + bn + 8 <= N) {
        const float4* bp = (const float4*)(B + (size_t)gk * N + n0 + bn);
        float4 u0 = bp[0], u1 = bp[1];
        tb[0]=u0.x; tb[1]=u0.y; tb[2]=u0.z; tb[3]=u0.w;
        tb[4]=u1.x; tb[5]=u1.y; tb[6]=u1.z; tb[7]=u1.w;
      } else {
        #pragma unroll
        for (int q = 0; q < 8; q++) {
          int gn = n0 + bn + q;
          tb[q] = (gk < K && gn < N) ? B[(size_t)gk * N + gn] : 0.f;
        }
      }
      #pragma unroll
      for (int q = 0; q < 8; q++) Bs[(bn + q) * LSTR + bk] = (__bf16)tb[q];
    }
    __syncthreads();
    // ---- compute ----
    bf16x8 af[4], bfr[2];
    #pragma unroll
    for (int mf = 0; mf < 4; mf++)
      af[mf] = *(const bf16x8*)&As[(wm*64 + mf*16 + r) * LSTR + kg*8];
    #pragma unroll
    for (int nf = 0; nf < 2; nf++)
      bfr[nf] = *(const bf16x8*)&Bs[(wn*32 + nf*16 + r) * LSTR + kg*8];
    #pragma unroll
    for (int mf = 0; mf < 4; mf++)
      #pragma unroll
      for (int nf = 0; nf < 2; nf++)
        acc[mf][nf] = __builtin_amdgcn_mfma_f32_16x16x32_bf16(af[mf], bfr[nf], acc[mf][nf], 0, 0, 0);
  }

  // ---- epilogue ----
  #pragma unroll
  for (int mf = 0; mf < 4; mf++) {
    #pragma unroll
    for (int nf = 0; nf < 2; nf++) {
      #pragma unroll
      for (int q = 0; q < 4; q++) {
        int gm = m0 + wm*64 + mf*16 + kg*4 + q;
        int gn = n0 + wn*32 + nf*16 + r;
        if (gm < M && gn < N) {
          float v = acc[mf][nf][q];
          if (FLAGS & 2) v += bias[gn];
          if (FLAGS & 1) v = fmaxf(v, 0.f);
          C[(size_t)gm * ldc + gn] = v;
        }
      }
    }
  }
}

// ---------------- CSR build ----------------
__global__ void count_kernel(const int* __restrict__ dst, int* __restrict__ cnt, int E) {
  int e = blockIdx.x * 256 + threadIdx.x;
  if (e < E) atomicAdd(&cnt[dst[e]], 1);
}

__global__ __launch_bounds__(1024) void scan_kernel(const int* __restrict__ cnt,
                                                    int* __restrict__ rp, int n) {
  __shared__ int wpart[16];
  __shared__ int carry_s, btot;
  int tid = threadIdx.x;
  int lane = tid & 63, wid = tid >> 6;
  if (tid == 0) carry_s = 0;
  __syncthreads();
  for (int base = 0; base < n; base += 1024) {
    int i = base + tid;
    int v = (i < n) ? cnt[i] : 0;
    int xv = v;
    #pragma unroll
    for (int off2 = 1; off2 < 64; off2 <<= 1) {
      int y = __shfl_up(xv, off2, 64);
      if (lane >= off2) xv += y;
    }
    if (lane == 63) wpart[wid] = xv;
    __syncthreads();
    if (tid == 0) {
      int s = 0;
      #pragma unroll
      for (int k = 0; k < 16; k++) { int t2 = wpart[k]; wpart[k] = s; s += t2; }
      btot = s;
    }
    __syncthreads();
    if (i < n) rp[i] = carry_s + wpart[wid] + xv - v;
    __syncthreads();
    if (tid == 0) carry_s += btot;
    __syncthreads();
  }
  if (tid == 0) rp[n] = carry_s;
}

__global__ void dinv_kernel(const int* __restrict__ cnt, float* __restrict__ dinv, int n) {
  int v = blockIdx.x * 256 + threadIdx.x;
  if (v < n) dinv[v] = rsqrtf((float)(cnt[v] + 1));
}

__global__ void fill_kernel(const int* __restrict__ src, const int* __restrict__ dst,
                            const int* __restrict__ rp, int* __restrict__ fil,
                            int* __restrict__ csr, int* __restrict__ csr_dst, int E) {
  int e = blockIdx.x * 256 + threadIdx.x;
  if (e < E) {
    int d = dst[e];
    int pos = rp[d] + atomicAdd(&fil[d], 1);
    csr[pos] = src[e];
    csr_dst[pos] = d;
  }
}

// ---------------- GCN aggregate (wave/node, chunked edge preload) ----------
__global__ void gcn_agg_kernel(const float* __restrict__ h, const int* __restrict__ rp,
                               const int* __restrict__ csr, const float* __restrict__ dinv,
                               const float* __restrict__ bias, float* __restrict__ out, int n)
{
  const int lane = threadIdx.x & 63;
  const int v = blockIdx.x * 4 + (threadIdx.x >> 6);
  if (v >= n) return;
  const float dv = dinv[v];
  const int e0 = rp[v], e1 = rp[v + 1];
  float acc[5];
  #pragma unroll
  for (int j = 0; j < 5; j++) acc[j] = dv * h[(size_t)v * FDIM + lane + 64 * j];
  for (int base = e0; base < e1; base += 64) {
    int nn = min(64, e1 - base);
    int s_l = (lane < nn) ? csr[base + lane] : 0;
    float d_l = (lane < nn) ? dinv[s_l] : 0.f;
    for (int j2 = 0; j2 < nn; j2++) {
      int sj = __shfl(s_l, j2, 64);
      float cj = __shfl(d_l, j2, 64);
      const float* hs = h + (size_t)sj * FDIM;
      #pragma unroll
      for (int j = 0; j < 5; j++) acc[j] += cj * hs[lane + 64 * j];
    }
  }
  #pragma unroll
  for (int j = 0; j < 5; j++) {
    float rr = dv * acc[j] + bias[lane + 64 * j];
    out[(size_t)v * FDIM + lane + 64 * j] = fmaxf(rr, 0.f);
  }
}

// ---------------- GAT attention scores a_s, a_d (one wave per node) --------
__global__ void gat_scores_kernel(const float* __restrict__ h, const float* __restrict__ att_s,
                                  const float* __restrict__ att_d, float* __restrict__ as_,
                                  float* __restrict__ ad_, int n)
{
  const int lane = threadIdx.x & 63;
  const int v = blockIdx.x * 4 + (threadIdx.x >> 6);
  if (v >= n) return;
  const int c = lane & 31;
  const int hh = lane >> 5;
  #pragma unroll
  for (int j = 0; j < 5; j++) {
    int head = hh * 5 + j;
    float xv = h[(size_t)v * FDIM + head * 32 + c];
    float ps = xv * att_s[head * 32 + c];
    float pd = xv * att_d[head * 32 + c];
    #pragma unroll
    for (int off = 1; off < 32; off <<= 1) {
      ps += __shfl_xor(ps, off, 64);
      pd += __shfl_xor(pd, off, 64);
    }
    if (c == 0) { as_[v * NHEADS + head] = ps; ad_[v * NHEADS + head] = pd; }
  }
}

__device__ __forceinline__ float lrelu(float x) { return x > 0.f ? x : 0.2f * x; }

// ---------------- edge-parallel raw scores (CSR order) ----------------
__global__ void escore_kernel(const int* __restrict__ csr, const int* __restrict__ csr_dst,
                              const float* __restrict__ as_, const float* __restrict__ ad_,
                              float* __restrict__ es, int E)
{
  int i = blockIdx.x * 256 + threadIdx.x;
  if (i >= E) return;
  int s = csr[i], d = csr_dst[i];
  const float* ap = as_ + (size_t)s * NHEADS;
  const float* dp = ad_ + (size_t)d * NHEADS;
  float* ep = es + (size_t)i * NHEADS;
  #pragma unroll
  for (int t = 0; t < NHEADS; t++) ep[t] = lrelu(ap[t] + dp[t]);
}

// ---------------- per-(node,head) segment max + denom ----------------
__global__ void mdenom_kernel(const float* __restrict__ es, const int* __restrict__ rp,
                              const float* __restrict__ as_, const float* __restrict__ ad_,
                              float* __restrict__ mseg, float* __restrict__ invden,
                              float* __restrict__ aself, int n)
{
  int tid = blockIdx.x * 256 + threadIdx.x;
  if (tid >= n * NHEADS) return;
  int v = tid / NHEADS, t = tid - v * NHEADS;
  int e0 = rp[v], e1 = rp[v + 1];
  float esf = lrelu(as_[tid] + ad_[tid]);
  float m = esf;
  for (int e = e0; e < e1; e++) m = fmaxf(m, es[(size_t)e * NHEADS + t]);
  float den = __expf(esf - m);
  float pself = den;
  for (int e = e0; e < e1; e++) den += __expf(es[(size_t)e * NHEADS + t] - m);
  float inv = 1.f / den;
  mseg[tid] = m;
  invden[tid] = inv;
  aself[tid] = pself * inv;
}

// ---------------- edge-parallel alpha (in-place on es) ----------------
__global__ void alpha_kernel(const int* __restrict__ csr_dst, const float* __restrict__ mseg,
                             const float* __restrict__ invden, float* __restrict__ es, int E)
{
  int i = blockIdx.x * 256 + threadIdx.x;
  if (i >= E) return;
  int d = csr_dst[i];
  const float* mp = mseg + (size_t)d * NHEADS;
  const float* ip = invden + (size_t)d * NHEADS;
  float* ep = es + (size_t)i * NHEADS;
  #pragma unroll
  for (int t = 0; t < NHEADS; t++) ep[t] = __expf(ep[t] - mp[t]) * ip[t];
}

// ---------------- GAT aggregate (wave/node, chunked edge preload) ----------
__global__ void gat_agg_kernel(const float* __restrict__ h, const int* __restrict__ rp,
                               const int* __restrict__ csr, const float* __restrict__ alpha,
                               const float* __restrict__ aself, const float* __restrict__ bias,
                               float* __restrict__ out, int n)
{
  const int lane = threadIdx.x & 63;
  const int v = blockIdx.x * 4 + (threadIdx.x >> 6);
  if (v >= n) return;
  const int hb = lane >> 5;   // head of channel lane+64j is 2j+hb
  const int e0 = rp[v], e1 = rp[v + 1];
  const float* asf = aself + (size_t)v * NHEADS;
  float acc[5];
  #pragma unroll
  for (int j = 0; j < 5; j++)
    acc[j] = asf[2 * j + hb] * h[(size_t)v * FDIM + lane + 64 * j];
  for (int base = e0; base < e1; base += 64) {
    int nn = min(64, e1 - base);
    int s_l = (lane < nn) ? csr[base + lane] : 0;
    for (int j2 = 0; j2 < nn; j2++) {
      int sj = __shfl(s_l, j2, 64);
      const float* al = alpha + (size_t)(base + j2) * NHEADS;
      const float* hs = h + (size_t)sj * FDIM;
      #pragma unroll
      for (int j = 0; j < 5; j++) acc[j] += al[2 * j + hb] * hs[lane + 64 * j];
    }
  }
  #pragma unroll
  for (int j = 0; j < 5; j++) {
    int c = lane + 64 * j;
    float rr = acc[j] + bias[c];
    out[(size_t)v * FDIM + c] = fmaxf(rr, 0.f);
  }
}

// ---------------- batch boundaries + pooling ----------------
__global__ void bstart_kernel(const int* __restrict__ batch, int* __restrict__ bstart,
                              int n, int B_) {
  int v = blockIdx.x * 256 + threadIdx.x;
  if (v > n) return;
  int bv = (v < n) ? batch[v] : B_;
  int bp = (v == 0) ? -1 : batch[v - 1];
  for (int gg = bp + 1; gg <= bv; gg++) bstart[gg] = v;
}

__global__ void pool_kernel(const float* __restrict__ xin, const int* __restrict__ bstart,
                            float* __restrict__ g) {
  int gid = blockIdx.x;
  int c = threadIdx.x;  // 320 threads
  int s = bstart[gid], e = bstart[gid + 1];
  float mx = -__builtin_inff(), sm = 0.f;
  for (int v = s; v < e; v++) {
    float val = xin[(size_t)v * FDIM + c];
    mx = fmaxf(mx, val);
    sm += val;
  }
  float cntf = (float)(e - s);
  g[gid * (2 * FDIM) + c] = mx;
  g[gid * (2 * FDIM) + FDIM + c] = sm / fmaxf(cntf, 1.f);
}

// ---------------- launch ----------------
extern "C" void kernel_launch(void* const* d_in, const int* in_sizes, int n_in,
                              void* d_out, int out_size, void* d_ws, size_t ws_size,
                              hipStream_t stream)
{
  const int N = in_sizes[0] / FDIM;
  const int E = in_sizes[2] / 2;

  const float* x[2]   = {(const float*)d_in[0], (const float*)d_in[1]};
  const int*   ei[2]  = {(const int*)d_in[2], (const int*)d_in[3]};
  const int*   bat[2] = {(const int*)d_in[4], (const int*)d_in[5]};
  const float* W_gcn   = (const float*)d_in[6];
  const float* b_gcn   = (const float*)d_in[7];
  const float* W_gat   = (const float*)d_in[8];
  const float* att_src = (const float*)d_in[9];
  const float* att_dst = (const float*)d_in[10];
  const float* b_gat   = (const float*)d_in[11];
  const float* W_fc_g1 = (const float*)d_in[12];
  const float* b_fc_g1 = (const float*)d_in[13];
  const float* W_fc_g2 = (const float*)d_in[14];
  const float* b_fc_g2 = (const float*)d_in[15];
  const float* W_fc1   = (const float*)d_in[16];
  const float* b_fc1   = (const float*)d_in[17];
  const float* W_fc2   = (const float*)d_in[18];
  const float* b_fc2   = (const float*)d_in[19];
  const float* W_out   = (const float*)d_in[20];
  const float* b_out   = (const float*)d_in[21];
  float* outp = (float*)d_out;

  char* ws = (char*)d_ws;
  size_t off = 0;
  auto alloc = [&](size_t bytes) -> char* {
    char* p = ws + off;
    off += (bytes + 255) & ~(size_t)255;
    return p;
  };
  int*   cnt    = (int*)alloc((size_t)N * 4);
  int*   fil    = (int*)alloc((size_t)N * 4);
  int*   rp     = (int*)alloc((size_t)(N + 1) * 4);
  int*   csr    = (int*)alloc((size_t)E * 4);
  int*   csrd   = (int*)alloc((size_t)E * 4);
  float* dinv   = (float*)alloc((size_t)N * 4);
  int*   bstart = (int*)alloc((size_t)(NGR + 1) * 4);
  float* hbuf   = (float*)alloc((size_t)N * FDIM * 4);
  float* xbuf   = (float*)alloc((size_t)N * FDIM * 4);
  float* as_    = (float*)alloc((size_t)N * NHEADS * 4);
  float* ad_    = (float*)alloc((size_t)N * NHEADS * 4);
  float* es     = (float*)alloc((size_t)E * NHEADS * 4);
  float* mseg   = (float*)alloc((size_t)N * NHEADS * 4);
  float* invden = (float*)alloc((size_t)N * NHEADS * 4);
  float* aself  = (float*)alloc((size_t)N * NHEADS * 4);
  float* g      = (float*)alloc((size_t)NGR * 2 * FDIM * 4);
  float* t1     = (float*)alloc((size_t)NGR * 1500 * 4);
  float* xc     = (float*)alloc((size_t)NGR * 256 * 4);
  float* t2     = (float*)alloc((size_t)NGR * 1024 * 4);
  float* t3     = (float*)alloc((size_t)NGR * 512 * 4);
  if (off > ws_size) return;  // workspace too small: bail (visible as absmax fail)

  for (int br = 0; br < 2; br++) {
    hipMemsetAsync(cnt, 0, (size_t)N * 4, stream);
    hipMemsetAsync(fil, 0, (size_t)N * 4, stream);
    const int* srcp = ei[br];
    const int* dstp = ei[br] + E;
    count_kernel<<<(E + 255) / 256, 256, 0, stream>>>(dstp, cnt, E);
    scan_kernel<<<1, 1024, 0, stream>>>(cnt, rp, N);
    dinv_kernel<<<(N + 255) / 256, 256, 0, stream>>>(cnt, dinv, N);
    fill_kernel<<<(E + 255) / 256, 256, 0, stream>>>(srcp, dstp, rp, fil, csr, csrd, E);

    dim3 gbig((N + BM - 1) / BM, (FDIM + BN - 1) / BN);
    gemm_bf16_kernel<0><<<gbig, 256, 0, stream>>>(x[br], W_gcn, hbuf, nullptr, N, FDIM, FDIM, FDIM);
    gcn_agg_kernel<<<(N + 3) / 4, 256, 0, stream>>>(hbuf, rp, csr, dinv, b_gcn, xbuf, N);
    gemm_bf16_kernel<0><<<gbig, 256, 0, stream>>>(xbuf, W_gat, hbuf, nullptr, N, FDIM, FDIM, FDIM);
    gat_scores_kernel<<<(N + 3) / 4, 256, 0, stream>>>(hbuf, att_src, att_dst, as_, ad_, N);

    escore_kernel<<<(E + 255) / 256, 256, 0, stream>>>(csr, csrd, as_, ad_, es, E);
    mdenom_kernel<<<(N * NHEADS + 255) / 256, 256, 0, stream>>>(es, rp, as_, ad_, mseg, invden, aself, N);
    alpha_kernel<<<(E + 255) / 256, 256, 0, stream>>>(csrd, mseg, invden, es, E);
    gat_agg_kernel<<<(N + 3) / 4, 256, 0, stream>>>(hbuf, rp, csr, es, aself, b_gat, xbuf, N);

    bstart_kernel<<<(N + 256) / 256, 256, 0, stream>>>(bat[br], bstart, N, NGR);
    pool_kernel<<<NGR, FDIM, 0, stream>>>(xbuf, bstart, g);

    dim3 gfc1((NGR + BM - 1) / BM, (1500 + BN - 1) / BN);
    gemm_bf16_kernel<3><<<gfc1, 256, 0, stream>>>(g, W_fc_g1, t1, b_fc_g1, NGR, 1500, 2 * FDIM, 1500);
    dim3 gfc2((NGR + BM - 1) / BM, (128 + BN - 1) / BN);
    gemm_bf16_kernel<2><<<gfc2, 256, 0, stream>>>(t1, W_fc_g2, xc + br * 128, b_fc_g2, NGR, 128, 1500, 256);
  }

  dim3 gx1((NGR + BM - 1) / BM, (1024 + BN - 1) / BN);
  gemm_bf16_kernel<3><<<gx1, 256, 0, stream>>>(xc, W_fc1, t2, b_fc1, NGR, 1024, 256, 1024);
  dim3 gx2((NGR + BM - 1) / BM, (512 + BN - 1) / BN);
  gemm_bf16_kernel<3><<<gx2, 256, 0, stream>>>(t2, W_fc2, t3, b_fc2, NGR, 512, 1024, 512);
  dim3 gx3((NGR + BM - 1) / BM, 1);
  gemm_bf16_kernel<2><<<gx3, 256, 0, stream>>>(t3, W_out, outp, b_out, NGR, 2, 512, 2);
}

// Round 3
// 1082.802 us; speedup vs baseline: 2.2679x; 1.2969x over previous
//
#include <hip/hip_runtime.h>
#include <type_traits>

#define FDIM 320
#define NHEADS 10
#define NGR 256

typedef __bf16 bf16x8 __attribute__((ext_vector_type(8)));
typedef float f32x4 __attribute__((ext_vector_type(4)));

// ---------------- GEMM: C[M,N] = A[M,K] * B[K,N] (f32 weights), bf16 MFMA --
#define BM 128
#define BN 64
#define BK 32
#define LSTR 56   // LDS row stride in elems: 112B, 16B-aligned, 2-way bank alias only

template<int FLAGS, typename TA, typename TC>  // FLAGS bit0: relu, bit1: bias
__global__ __launch_bounds__(256) void gemm_bf16_kernel(
    const TA* __restrict__ A, const float* __restrict__ B,
    TC* __restrict__ C, const float* __restrict__ bias,
    int M, int N, int K, int ldc)
{
  __shared__ __bf16 As[BM * LSTR];
  __shared__ __bf16 Bs[BN * LSTR];

  const int tid = threadIdx.x;
  const int lane = tid & 63;
  const int w = tid >> 6;
  const int wm = w >> 1, wn = w & 1;     // 2x2 waves, each 64x32 out
  const int r = lane & 15, kg = lane >> 4;
  const int m0 = blockIdx.x * BM, n0 = blockIdx.y * BN;

  f32x4 acc[4][2];
  #pragma unroll
  for (int i = 0; i < 4; i++)
    #pragma unroll
    for (int j = 0; j < 2; j++)
      acc[i][j] = (f32x4){0.f, 0.f, 0.f, 0.f};

  const int arow = tid >> 1, ahalf = tid & 1;     // A stage: 16 elems/thread
  const int bk = tid >> 3, bn = (tid & 7) * 8;    // B stage: 8 f32/thread

  for (int k0 = 0; k0 < K; k0 += BK) {
    __syncthreads();
    // ---- stage A tile [BM x BK] ----
    {
      int gm = m0 + arow;
      int kbase = k0 + ahalf * 16;
      bf16x8 v0, v1;
      if constexpr (std::is_same_v<TA, float>) {
        float tmp[16];
        if (gm < M && kbase + 16 <= K) {
          const float4* ap = (const float4*)(A + (size_t)gm * K + kbase);
          #pragma unroll
          for (int q = 0; q < 4; q++) {
            float4 v = ap[q];
            tmp[q*4+0] = v.x; tmp[q*4+1] = v.y; tmp[q*4+2] = v.z; tmp[q*4+3] = v.w;
          }
        } else {
          #pragma unroll
          for (int q = 0; q < 16; q++) {
            int kk = kbase + q;
            tmp[q] = (gm < M && kk < K) ? A[(size_t)gm * K + kk] : 0.f;
          }
        }
        #pragma unroll
        for (int q = 0; q < 8; q++) { v0[q] = (__bf16)tmp[q]; v1[q] = (__bf16)tmp[q+8]; }
      } else {
        if (gm < M && kbase + 16 <= K) {
          const bf16x8* ap = (const bf16x8*)(A + (size_t)gm * K + kbase);
          v0 = ap[0]; v1 = ap[1];
        } else {
          #pragma unroll
          for (int q = 0; q < 8; q++) {
            int k1 = kbase + q, k2 = kbase + 8 + q;
            v0[q] = (gm < M && k1 < K) ? A[(size_t)gm * K + k1] : (__bf16)0.f;
            v1[q] = (gm < M && k2 < K) ? A[(size_t)gm * K + k2] : (__bf16)0.f;
          }
        }
      }
      bf16x8* dp = (bf16x8*)&As[arow * LSTR + ahalf * 16];
      dp[0] = v0; dp[1] = v1;
    }
    // ---- stage B tile transposed: Bs[n][k] = B[k0+k][n0+n] ----
    {
      int gk = k0 + bk;
      float tb[8];
      if (gk < K && n0 + bn + 8 <= N) {
        const float4* bp = (const float4*)(B + (size_t)gk * N + n0 + bn);
        float4 u0 = bp[0], u1 = bp[1];
        tb[0]=u0.x; tb[1]=u0.y; tb[2]=u0.z; tb[3]=u0.w;
        tb[4]=u1.x; tb[5]=u1.y; tb[6]=u1.z; tb[7]=u1.w;
      } else {
        #pragma unroll
        for (int q = 0; q < 8; q++) {
          int gn = n0 + bn + q;
          tb[q] = (gk < K && gn < N) ? B[(size_t)gk * N + gn] : 0.f;
        }
      }
      #pragma unroll
      for (int q = 0; q < 8; q++) Bs[(bn + q) * LSTR + bk] = (__bf16)tb[q];
    }
    __syncthreads();
    // ---- compute ----
    bf16x8 af[4], bfr[2];
    #pragma unroll
    for (int mf = 0; mf < 4; mf++)
      af[mf] = *(const bf16x8*)&As[(wm*64 + mf*16 + r) * LSTR + kg*8];
    #pragma unroll
    for (int nf = 0; nf < 2; nf++)
      bfr[nf] = *(const bf16x8*)&Bs[(wn*32 + nf*16 + r) * LSTR + kg*8];
    #pragma unroll
    for (int mf = 0; mf < 4; mf++)
      #pragma unroll
      for (int nf = 0; nf < 2; nf++)
        acc[mf][nf] = __builtin_amdgcn_mfma_f32_16x16x32_bf16(af[mf], bfr[nf], acc[mf][nf], 0, 0, 0);
  }

  // ---- epilogue ----
  #pragma unroll
  for (int mf = 0; mf < 4; mf++) {
    #pragma unroll
    for (int nf = 0; nf < 2; nf++) {
      #pragma unroll
      for (int q = 0; q < 4; q++) {
        int gm = m0 + wm*64 + mf*16 + kg*4 + q;
        int gn = n0 + wn*32 + nf*16 + r;
        if (gm < M && gn < N) {
          float v = acc[mf][nf][q];
          if (FLAGS & 2) v += bias[gn];
          if (FLAGS & 1) v = fmaxf(v, 0.f);
          C[(size_t)gm * ldc + gn] = (TC)v;
        }
      }
    }
  }
}

// ---------------- CSR build ----------------
__global__ void count_kernel(const int* __restrict__ dst, int* __restrict__ cnt, int E) {
  int e = blockIdx.x * 256 + threadIdx.x;
  if (e < E) atomicAdd(&cnt[dst[e]], 1);
}

// hierarchical scan: block sums -> scan of sums -> per-block rescan
__global__ void bsum_kernel(const int* __restrict__ cnt, int* __restrict__ bsum, int n) {
  __shared__ int wp[4];
  int tid = threadIdx.x, lane = tid & 63, wid = tid >> 6;
  int i = blockIdx.x * 256 + tid;
  int v = (i < n) ? cnt[i] : 0;
  #pragma unroll
  for (int off = 32; off >= 1; off >>= 1) v += __shfl_xor(v, off, 64);
  if (lane == 0) wp[wid] = v;
  __syncthreads();
  if (tid == 0) bsum[blockIdx.x] = wp[0] + wp[1] + wp[2] + wp[3];
}

__global__ void bscan_kernel(int* __restrict__ bsum, int nb) {
  __shared__ int wp[4];
  int tid = threadIdx.x, lane = tid & 63, wid = tid >> 6;
  int v = (tid < nb) ? bsum[tid] : 0;
  int xv = v;
  #pragma unroll
  for (int off = 1; off < 64; off <<= 1) {
    int y = __shfl_up(xv, off, 64);
    if (lane >= off) xv += y;
  }
  if (lane == 63) wp[wid] = xv;
  __syncthreads();
  if (tid == 0) { int s = 0; for (int k = 0; k < 4; k++) { int t = wp[k]; wp[k] = s; s += t; } }
  __syncthreads();
  if (tid < nb) bsum[tid] = wp[wid] + xv - v;   // exclusive
}

__global__ void rpfill_kernel(const int* __restrict__ cnt, const int* __restrict__ bsum,
                              int* __restrict__ rp, int n, int E) {
  __shared__ int wp[4];
  int tid = threadIdx.x, lane = tid & 63, wid = tid >> 6;
  int i = blockIdx.x * 256 + tid;
  int v = (i < n) ? cnt[i] : 0;
  int xv = v;
  #pragma unroll
  for (int off = 1; off < 64; off <<= 1) {
    int y = __shfl_up(xv, off, 64);
    if (lane >= off) xv += y;
  }
  if (lane == 63) wp[wid] = xv;
  __syncthreads();
  if (tid == 0) { int s = 0; for (int k = 0; k < 4; k++) { int t = wp[k]; wp[k] = s; s += t; } }
  __syncthreads();
  if (i < n) rp[i] = bsum[blockIdx.x] + wp[wid] + xv - v;
  if (blockIdx.x == 0 && tid == 0) rp[n] = E;
}

__global__ void dinv_kernel(const int* __restrict__ cnt, float* __restrict__ dinv, int n) {
  int v = blockIdx.x * 256 + threadIdx.x;
  if (v < n) dinv[v] = rsqrtf((float)(cnt[v] + 1));
}

__global__ void fill_kernel(const int* __restrict__ src, const int* __restrict__ dst,
                            const int* __restrict__ rp, int* __restrict__ fil,
                            int* __restrict__ csr, int* __restrict__ csr_dst, int E) {
  int e = blockIdx.x * 256 + threadIdx.x;
  if (e < E) {
    int d = dst[e];
    int pos = rp[d] + atomicAdd(&fil[d], 1);
    csr[pos] = src[e];
    csr_dst[pos] = d;
  }
}

// ---------------- GCN aggregate (wave/node, chunked edge preload, bf16 h) --
__global__ void gcn_agg_kernel(const __bf16* __restrict__ h, const int* __restrict__ rp,
                               const int* __restrict__ csr, const float* __restrict__ dinv,
                               const float* __restrict__ bias, __bf16* __restrict__ out, int n)
{
  const int lane = threadIdx.x & 63;
  const int v = blockIdx.x * 4 + (threadIdx.x >> 6);
  if (v >= n) return;
  const float dv = dinv[v];
  const int e0 = rp[v], e1 = rp[v + 1];
  float acc[5];
  #pragma unroll
  for (int j = 0; j < 5; j++) acc[j] = dv * (float)h[(size_t)v * FDIM + lane + 64 * j];
  for (int base = e0; base < e1; base += 64) {
    int nn = min(64, e1 - base);
    int s_l = (lane < nn) ? csr[base + lane] : 0;
    float d_l = (lane < nn) ? dinv[s_l] : 0.f;
    for (int j2 = 0; j2 < nn; j2++) {
      int sj = __shfl(s_l, j2, 64);
      float cj = __shfl(d_l, j2, 64);
      const __bf16* hs = h + (size_t)sj * FDIM;
      #pragma unroll
      for (int j = 0; j < 5; j++) acc[j] += cj * (float)hs[lane + 64 * j];
    }
  }
  #pragma unroll
  for (int j = 0; j < 5; j++) {
    float rr = dv * acc[j] + bias[lane + 64 * j];
    out[(size_t)v * FDIM + lane + 64 * j] = (__bf16)fmaxf(rr, 0.f);
  }
}

// ---------------- GAT attention scores a_s, a_d (one wave per node) --------
__global__ void gat_scores_kernel(const __bf16* __restrict__ h, const float* __restrict__ att_s,
                                  const float* __restrict__ att_d, float* __restrict__ as_,
                                  float* __restrict__ ad_, int n)
{
  const int lane = threadIdx.x & 63;
  const int v = blockIdx.x * 4 + (threadIdx.x >> 6);
  if (v >= n) return;
  const int c = lane & 31;
  const int hh = lane >> 5;
  #pragma unroll
  for (int j = 0; j < 5; j++) {
    int head = hh * 5 + j;
    float xv = (float)h[(size_t)v * FDIM + head * 32 + c];
    float ps = xv * att_s[head * 32 + c];
    float pd = xv * att_d[head * 32 + c];
    #pragma unroll
    for (int off = 1; off < 32; off <<= 1) {
      ps += __shfl_xor(ps, off, 64);
      pd += __shfl_xor(pd, off, 64);
    }
    if (c == 0) { as_[v * NHEADS + head] = ps; ad_[v * NHEADS + head] = pd; }
  }
}

__device__ __forceinline__ float lrelu(float x) { return x > 0.f ? x : 0.2f * x; }

// ---------------- edge-parallel raw scores (CSR order) ----------------
__global__ void escore_kernel(const int* __restrict__ csr, const int* __restrict__ csr_dst,
                              const float* __restrict__ as_, const float* __restrict__ ad_,
                              float* __restrict__ es, int E)
{
  int i = blockIdx.x * 256 + threadIdx.x;
  if (i >= E) return;
  int s = csr[i], d = csr_dst[i];
  const float* ap = as_ + (size_t)s * NHEADS;
  const float* dp = ad_ + (size_t)d * NHEADS;
  float* ep = es + (size_t)i * NHEADS;
  #pragma unroll
  for (int t = 0; t < NHEADS; t++) ep[t] = lrelu(ap[t] + dp[t]);
}

// ---------------- per-(node,head) segment max + denom ----------------
__global__ void mdenom_kernel(const float* __restrict__ es, const int* __restrict__ rp,
                              const float* __restrict__ as_, const float* __restrict__ ad_,
                              float* __restrict__ mseg, float* __restrict__ invden,
                              float* __restrict__ aself, int n)
{
  int tid = blockIdx.x * 256 + threadIdx.x;
  if (tid >= n * NHEADS) return;
  int v = tid / NHEADS, t = tid - v * NHEADS;
  int e0 = rp[v], e1 = rp[v + 1];
  float esf = lrelu(as_[tid] + ad_[tid]);
  float m = esf;
  for (int e = e0; e < e1; e++) m = fmaxf(m, es[(size_t)e * NHEADS + t]);
  float den = __expf(esf - m);
  float pself = den;
  for (int e = e0; e < e1; e++) den += __expf(es[(size_t)e * NHEADS + t] - m);
  float inv = 1.f / den;
  mseg[tid] = m;
  invden[tid] = inv;
  aself[tid] = pself * inv;
}

// ---------------- edge-parallel alpha (in-place on es) ----------------
__global__ void alpha_kernel(const int* __restrict__ csr_dst, const float* __restrict__ mseg,
                             const float* __restrict__ invden, float* __restrict__ es, int E)
{
  int i = blockIdx.x * 256 + threadIdx.x;
  if (i >= E) return;
  int d = csr_dst[i];
  const float* mp = mseg + (size_t)d * NHEADS;
  const float* ip = invden + (size_t)d * NHEADS;
  float* ep = es + (size_t)i * NHEADS;
  #pragma unroll
  for (int t = 0; t < NHEADS; t++) ep[t] = __expf(ep[t] - mp[t]) * ip[t];
}

// ---------------- GAT aggregate (wave/node, chunked edge preload, bf16 h) --
__global__ void gat_agg_kernel(const __bf16* __restrict__ h, const int* __restrict__ rp,
                               const int* __restrict__ csr, const float* __restrict__ alpha,
                               const float* __restrict__ aself, const float* __restrict__ bias,
                               __bf16* __restrict__ out, int n)
{
  const int lane = threadIdx.x & 63;
  const int v = blockIdx.x * 4 + (threadIdx.x >> 6);
  if (v >= n) return;
  const int hb = lane >> 5;   // head of channel lane+64j is 2j+hb
  const int e0 = rp[v], e1 = rp[v + 1];
  const float* asf = aself + (size_t)v * NHEADS;
  float acc[5];
  #pragma unroll
  for (int j = 0; j < 5; j++)
    acc[j] = asf[2 * j + hb] * (float)h[(size_t)v * FDIM + lane + 64 * j];
  for (int base = e0; base < e1; base += 64) {
    int nn = min(64, e1 - base);
    int s_l = (lane < nn) ? csr[base + lane] : 0;
    for (int j2 = 0; j2 < nn; j2++) {
      int sj = __shfl(s_l, j2, 64);
      const float* al = alpha + (size_t)(base + j2) * NHEADS;
      const __bf16* hs = h + (size_t)sj * FDIM;
      #pragma unroll
      for (int j = 0; j < 5; j++) acc[j] += al[2 * j + hb] * (float)hs[lane + 64 * j];
    }
  }
  #pragma unroll
  for (int j = 0; j < 5; j++) {
    int c = lane + 64 * j;
    float rr = acc[j] + bias[c];
    out[(size_t)v * FDIM + c] = (__bf16)fmaxf(rr, 0.f);
  }
}

// ---------------- batch boundaries + pooling ----------------
__global__ void bstart_kernel(const int* __restrict__ batch, int* __restrict__ bstart,
                              int n, int B_) {
  int v = blockIdx.x * 256 + threadIdx.x;
  if (v > n) return;
  int bv = (v < n) ? batch[v] : B_;
  int bp = (v == 0) ? -1 : batch[v - 1];
  for (int gg = bp + 1; gg <= bv; gg++) bstart[gg] = v;
}

__global__ void pool_kernel(const __bf16* __restrict__ xin, const int* __restrict__ bstart,
                            float* __restrict__ g) {
  int gid = blockIdx.x;
  int c = blockIdx.y * 64 + threadIdx.x;
  int s = bstart[gid], e = bstart[gid + 1];
  float mx = -__builtin_inff(), sm = 0.f;
  for (int v = s; v < e; v++) {
    float val = (float)xin[(size_t)v * FDIM + c];
    mx = fmaxf(mx, val);
    sm += val;
  }
  float cntf = (float)(e - s);
  g[gid * (2 * FDIM) + c] = mx;
  g[gid * (2 * FDIM) + FDIM + c] = sm / fmaxf(cntf, 1.f);
}

// ---------------- launch ----------------
extern "C" void kernel_launch(void* const* d_in, const int* in_sizes, int n_in,
                              void* d_out, int out_size, void* d_ws, size_t ws_size,
                              hipStream_t stream)
{
  const int N = in_sizes[0] / FDIM;
  const int E = in_sizes[2] / 2;
  const int NB = (N + 255) / 256;

  const float* x[2]   = {(const float*)d_in[0], (const float*)d_in[1]};
  const int*   ei[2]  = {(const int*)d_in[2], (const int*)d_in[3]};
  const int*   bat[2] = {(const int*)d_in[4], (const int*)d_in[5]};
  const float* W_gcn   = (const float*)d_in[6];
  const float* b_gcn   = (const float*)d_in[7];
  const float* W_gat   = (const float*)d_in[8];
  const float* att_src = (const float*)d_in[9];
  const float* att_dst = (const float*)d_in[10];
  const float* b_gat   = (const float*)d_in[11];
  const float* W_fc_g1 = (const float*)d_in[12];
  const float* b_fc_g1 = (const float*)d_in[13];
  const float* W_fc_g2 = (const float*)d_in[14];
  const float* b_fc_g2 = (const float*)d_in[15];
  const float* W_fc1   = (const float*)d_in[16];
  const float* b_fc1   = (const float*)d_in[17];
  const float* W_fc2   = (const float*)d_in[18];
  const float* b_fc2   = (const float*)d_in[19];
  const float* W_out   = (const float*)d_in[20];
  const float* b_out   = (const float*)d_in[21];
  float* outp = (float*)d_out;

  char* ws = (char*)d_ws;
  size_t off = 0;
  auto alloc = [&](size_t bytes) -> char* {
    char* p = ws + off;
    off += (bytes + 255) & ~(size_t)255;
    return p;
  };
  int*    cnt    = (int*)alloc((size_t)N * 4);
  int*    fil    = (int*)alloc((size_t)N * 4);
  int*    rp     = (int*)alloc((size_t)(N + 1) * 4);
  int*    bsum   = (int*)alloc((size_t)NB * 4);
  int*    csr    = (int*)alloc((size_t)E * 4);
  int*    csrd   = (int*)alloc((size_t)E * 4);
  float*  dinv   = (float*)alloc((size_t)N * 4);
  int*    bstart = (int*)alloc((size_t)(NGR + 1) * 4);
  __bf16* hbuf   = (__bf16*)alloc((size_t)N * FDIM * 2);
  __bf16* xbuf   = (__bf16*)alloc((size_t)N * FDIM * 2);
  float*  as_    = (float*)alloc((size_t)N * NHEADS * 4);
  float*  ad_    = (float*)alloc((size_t)N * NHEADS * 4);
  float*  es     = (float*)alloc((size_t)E * NHEADS * 4);
  float*  mseg   = (float*)alloc((size_t)N * NHEADS * 4);
  float*  invden = (float*)alloc((size_t)N * NHEADS * 4);
  float*  aself  = (float*)alloc((size_t)N * NHEADS * 4);
  float*  g      = (float*)alloc((size_t)NGR * 2 * FDIM * 4);
  float*  t1     = (float*)alloc((size_t)NGR * 1500 * 4);
  float*  xc     = (float*)alloc((size_t)NGR * 256 * 4);
  float*  t2     = (float*)alloc((size_t)NGR * 1024 * 4);
  float*  t3     = (float*)alloc((size_t)NGR * 512 * 4);
  if (off > ws_size) return;  // workspace too small: bail (visible as absmax fail)

  for (int br = 0; br < 2; br++) {
    hipMemsetAsync(cnt, 0, (size_t)N * 4, stream);
    hipMemsetAsync(fil, 0, (size_t)N * 4, stream);
    const int* srcp = ei[br];
    const int* dstp = ei[br] + E;
    count_kernel<<<(E + 255) / 256, 256, 0, stream>>>(dstp, cnt, E);
    bsum_kernel<<<NB, 256, 0, stream>>>(cnt, bsum, N);
    bscan_kernel<<<1, 256, 0, stream>>>(bsum, NB);
    rpfill_kernel<<<NB, 256, 0, stream>>>(cnt, bsum, rp, N, E);
    dinv_kernel<<<(N + 255) / 256, 256, 0, stream>>>(cnt, dinv, N);
    fill_kernel<<<(E + 255) / 256, 256, 0, stream>>>(srcp, dstp, rp, fil, csr, csrd, E);

    dim3 gbig((N + BM - 1) / BM, (FDIM + BN - 1) / BN);
    gemm_bf16_kernel<0, float, __bf16><<<gbig, 256, 0, stream>>>(x[br], W_gcn, hbuf, nullptr, N, FDIM, FDIM, FDIM);
    gcn_agg_kernel<<<(N + 3) / 4, 256, 0, stream>>>(hbuf, rp, csr, dinv, b_gcn, xbuf, N);
    gemm_bf16_kernel<0, __bf16, __bf16><<<gbig, 256, 0, stream>>>(xbuf, W_gat, hbuf, nullptr, N, FDIM, FDIM, FDIM);
    gat_scores_kernel<<<(N + 3) / 4, 256, 0, stream>>>(hbuf, att_src, att_dst, as_, ad_, N);

    escore_kernel<<<(E + 255) / 256, 256, 0, stream>>>(csr, csrd, as_, ad_, es, E);
    mdenom_kernel<<<(N * NHEADS + 255) / 256, 256, 0, stream>>>(es, rp, as_, ad_, mseg, invden, aself, N);
    alpha_kernel<<<(E + 255) / 256, 256, 0, stream>>>(csrd, mseg, invden, es, E);
    gat_agg_kernel<<<(N + 3) / 4, 256, 0, stream>>>(hbuf, rp, csr, es, aself, b_gat, xbuf, N);

    bstart_kernel<<<(N + 256) / 256, 256, 0, stream>>>(bat[br], bstart, N, NGR);
    dim3 gpool(NGR, FDIM / 64);
    pool_kernel<<<gpool, 64, 0, stream>>>(xbuf, bstart, g);

    dim3 gfc1((NGR + BM - 1) / BM, (1500 + BN - 1) / BN);
    gemm_bf16_kernel<3, float, float><<<gfc1, 256, 0, stream>>>(g, W_fc_g1, t1, b_fc_g1, NGR, 1500, 2 * FDIM, 1500);
    dim3 gfc2((NGR + BM - 1) / BM, (128 + BN - 1) / BN);
    gemm_bf16_kernel<2, float, float><<<gfc2, 256, 0, stream>>>(t1, W_fc_g2, xc + br * 128, b_fc_g2, NGR, 128, 1500, 256);
  }

  dim3 gx1((NGR + BM - 1) / BM, (1024 + BN - 1) / BN);
  gemm_bf16_kernel<3, float, float><<<gx1, 256, 0, stream>>>(xc, W_fc1, t2, b_fc1, NGR, 1024, 256, 1024);
  dim3 gx2((NGR + BM - 1) / BM, (512 + BN - 1) / BN);
  gemm_bf16_kernel<3, float, float><<<gx2, 256, 0, stream>>>(t2, W_fc2, t3, b_fc2, NGR, 512, 1024, 512);
  dim3 gx3((NGR + BM - 1) / BM, 1);
  gemm_bf16_kernel<2, float, float><<<gx3, 256, 0, stream>>>(t3, W_out, outp, b_out, NGR, 2, 512, 2);
}

// Round 4
// 1080.523 us; speedup vs baseline: 2.2727x; 1.0021x over previous
//
#include <hip/hip_runtime.h>
#include <type_traits>

#define FDIM 320
#define NHEADS 10
#define NGR 256

typedef __bf16 bf16x8 __attribute__((ext_vector_type(8)));
typedef float f32x4 __attribute__((ext_vector_type(4)));

// ---------------- weight transpose+convert: Wt[c*320+k] = (bf16)W[k*320+c] --
__global__ void wconv_kernel(const float* __restrict__ W, __bf16* __restrict__ Wt) {
  int idx = blockIdx.x * 256 + threadIdx.x;   // grid 400*256 = 102400
  int k = idx / FDIM, c = idx - k * FDIM;
  Wt[c * FDIM + k] = (__bf16)W[idx];
}

// ---------------- node GEMM: C[M,320] = A[M,320] * W[320,320], full-N tile -
// Wt is transposed bf16 [col][k]. 256 threads = 4 waves; wave (wr,wc) does
// rows wr*32..+32, cols wc*160..+160. BM=64, BK=32, 10 K-steps.
#define GLSTR 40   // LDS row stride elems (80B): 2-way bank alias on reads (free)

template<typename TA>
__global__ __launch_bounds__(256) void gemm320_kernel(
    const TA* __restrict__ A, const __bf16* __restrict__ Wt,
    __bf16* __restrict__ C, int M)
{
  __shared__ __bf16 As[64 * GLSTR];
  __shared__ __bf16 Bs[320 * GLSTR];

  const int tid = threadIdx.x;
  const int lane = tid & 63;
  const int w = tid >> 6;
  const int wr = w >> 1, wc = w & 1;
  const int r = lane & 15, kg = lane >> 4;
  const int m0 = blockIdx.x * 64;

  f32x4 acc0[10], acc1[10];
  #pragma unroll
  for (int i = 0; i < 10; i++) { acc0[i] = (f32x4){0,0,0,0}; acc1[i] = (f32x4){0,0,0,0}; }

  const int arow = tid >> 2, aq = tid & 3;   // A: 1 row-quarter (8 elems)/thread

  for (int k0 = 0; k0 < 320; k0 += 32) {
    __syncthreads();
    // ---- stage A [64 x 32] ----
    {
      int gm = m0 + arow;
      bf16x8 v = {};
      if (gm < M) {
        if constexpr (std::is_same_v<TA, float>) {
          const float4* ap = (const float4*)(A + (size_t)gm * FDIM + k0 + aq * 8);
          float4 u0 = ap[0], u1 = ap[1];
          v[0]=(__bf16)u0.x; v[1]=(__bf16)u0.y; v[2]=(__bf16)u0.z; v[3]=(__bf16)u0.w;
          v[4]=(__bf16)u1.x; v[5]=(__bf16)u1.y; v[6]=(__bf16)u1.z; v[7]=(__bf16)u1.w;
        } else {
          v = *(const bf16x8*)(A + (size_t)gm * FDIM + k0 + aq * 8);
        }
      }
      *(bf16x8*)&As[arow * GLSTR + aq * 8] = v;
    }
    // ---- stage B [320 cols x 32 k] from transposed bf16 weights ----
    {
      const bf16x8* sp = (const bf16x8*)(Wt + (size_t)tid * FDIM + k0);
      bf16x8 b0 = sp[0], b1 = sp[1], b2 = sp[2], b3 = sp[3];
      bf16x8* dp = (bf16x8*)&Bs[tid * GLSTR];
      dp[0] = b0; dp[1] = b1; dp[2] = b2; dp[3] = b3;
      if (tid < 64) {
        int c2 = 256 + tid;
        const bf16x8* sp2 = (const bf16x8*)(Wt + (size_t)c2 * FDIM + k0);
        bf16x8 c0 = sp2[0], c1 = sp2[1], c22 = sp2[2], c3 = sp2[3];
        bf16x8* dp2 = (bf16x8*)&Bs[c2 * GLSTR];
        dp2[0] = c0; dp2[1] = c1; dp2[2] = c22; dp2[3] = c3;
      }
    }
    __syncthreads();
    // ---- compute: 20 MFMA ----
    bf16x8 af0 = *(const bf16x8*)&As[(wr*32 + 0  + r) * GLSTR + kg*8];
    bf16x8 af1 = *(const bf16x8*)&As[(wr*32 + 16 + r) * GLSTR + kg*8];
    #pragma unroll
    for (int nf = 0; nf < 10; nf++) {
      bf16x8 bfr = *(const bf16x8*)&Bs[(wc*160 + nf*16 + r) * GLSTR + kg*8];
      acc0[nf] = __builtin_amdgcn_mfma_f32_16x16x32_bf16(af0, bfr, acc0[nf], 0, 0, 0);
      acc1[nf] = __builtin_amdgcn_mfma_f32_16x16x32_bf16(af1, bfr, acc1[nf], 0, 0, 0);
    }
  }

  // ---- epilogue: plain bf16 store ----
  #pragma unroll
  for (int nf = 0; nf < 10; nf++) {
    int gn = wc*160 + nf*16 + r;
    #pragma unroll
    for (int q = 0; q < 4; q++) {
      int gm0 = m0 + wr*32 + kg*4 + q;
      if (gm0 < M)      C[(size_t)gm0 * FDIM + gn]        = (__bf16)acc0[nf][q];
      int gm1 = gm0 + 16;
      if (gm1 < M)      C[(size_t)gm1 * FDIM + gn]        = (__bf16)acc1[nf][q];
    }
  }
}

// ---------------- generic GEMM (FC layers): C = A*B, f32 in/out ------------
#define BM 128
#define BN 64
#define BK 32
#define LSTR 56

template<int FLAGS>  // bit0: relu, bit1: bias
__global__ __launch_bounds__(256) void gemm_bf16_kernel(
    const float* __restrict__ A, const float* __restrict__ B,
    float* __restrict__ C, const float* __restrict__ bias,
    int M, int N, int K, int ldc)
{
  __shared__ __bf16 As[BM * LSTR];
  __shared__ __bf16 Bs[BN * LSTR];

  const int tid = threadIdx.x;
  const int lane = tid & 63;
  const int w = tid >> 6;
  const int wm = w >> 1, wn = w & 1;
  const int r = lane & 15, kg = lane >> 4;
  const int m0 = blockIdx.x * BM, n0 = blockIdx.y * BN;

  f32x4 acc[4][2];
  #pragma unroll
  for (int i = 0; i < 4; i++)
    #pragma unroll
    for (int j = 0; j < 2; j++)
      acc[i][j] = (f32x4){0.f, 0.f, 0.f, 0.f};

  const int arow = tid >> 1, ahalf = tid & 1;
  const int bk = tid >> 3, bn = (tid & 7) * 8;

  for (int k0 = 0; k0 < K; k0 += BK) {
    __syncthreads();
    {
      int gm = m0 + arow;
      int kbase = k0 + ahalf * 16;
      float tmp[16];
      if (gm < M && kbase + 16 <= K) {
        const float4* ap = (const float4*)(A + (size_t)gm * K + kbase);
        #pragma unroll
        for (int q = 0; q < 4; q++) {
          float4 v = ap[q];
          tmp[q*4+0] = v.x; tmp[q*4+1] = v.y; tmp[q*4+2] = v.z; tmp[q*4+3] = v.w;
        }
      } else {
        #pragma unroll
        for (int q = 0; q < 16; q++) {
          int kk = kbase + q;
          tmp[q] = (gm < M && kk < K) ? A[(size_t)gm * K + kk] : 0.f;
        }
      }
      bf16x8 v0, v1;
      #pragma unroll
      for (int q = 0; q < 8; q++) { v0[q] = (__bf16)tmp[q]; v1[q] = (__bf16)tmp[q+8]; }
      bf16x8* dp = (bf16x8*)&As[arow * LSTR + ahalf * 16];
      dp[0] = v0; dp[1] = v1;
    }
    {
      int gk = k0 + bk;
      float tb[8];
      if (gk < K && n0 + bn + 8 <= N) {
        const float4* bp = (const float4*)(B + (size_t)gk * N + n0 + bn);
        float4 u0 = bp[0], u1 = bp[1];
        tb[0]=u0.x; tb[1]=u0.y; tb[2]=u0.z; tb[3]=u0.w;
        tb[4]=u1.x; tb[5]=u1.y; tb[6]=u1.z; tb[7]=u1.w;
      } else {
        #pragma unroll
        for (int q = 0; q < 8; q++) {
          int gn = n0 + bn + q;
          tb[q] = (gk < K && gn < N) ? B[(size_t)gk * N + gn] : 0.f;
        }
      }
      #pragma unroll
      for (int q = 0; q < 8; q++) Bs[(bn + q) * LSTR + bk] = (__bf16)tb[q];
    }
    __syncthreads();
    bf16x8 af[4], bfr[2];
    #pragma unroll
    for (int mf = 0; mf < 4; mf++)
      af[mf] = *(const bf16x8*)&As[(wm*64 + mf*16 + r) * LSTR + kg*8];
    #pragma unroll
    for (int nf = 0; nf < 2; nf++)
      bfr[nf] = *(const bf16x8*)&Bs[(wn*32 + nf*16 + r) * LSTR + kg*8];
    #pragma unroll
    for (int mf = 0; mf < 4; mf++)
      #pragma unroll
      for (int nf = 0; nf < 2; nf++)
        acc[mf][nf] = __builtin_amdgcn_mfma_f32_16x16x32_bf16(af[mf], bfr[nf], acc[mf][nf], 0, 0, 0);
  }

  #pragma unroll
  for (int mf = 0; mf < 4; mf++) {
    #pragma unroll
    for (int nf = 0; nf < 2; nf++) {
      #pragma unroll
      for (int q = 0; q < 4; q++) {
        int gm = m0 + wm*64 + mf*16 + kg*4 + q;
        int gn = n0 + wn*32 + nf*16 + r;
        if (gm < M && gn < N) {
          float v = acc[mf][nf][q];
          if (FLAGS & 2) v += bias[gn];
          if (FLAGS & 1) v = fmaxf(v, 0.f);
          C[(size_t)gm * ldc + gn] = v;
        }
      }
    }
  }
}

// ---------------- CSR build ----------------
__global__ void count_kernel(const int* __restrict__ dst, int* __restrict__ cnt, int E) {
  int e = blockIdx.x * 256 + threadIdx.x;
  if (e < E) atomicAdd(&cnt[dst[e]], 1);
}

__global__ void bsum_kernel(const int* __restrict__ cnt, int* __restrict__ bsum, int n) {
  __shared__ int wp[4];
  int tid = threadIdx.x, lane = tid & 63, wid = tid >> 6;
  int i = blockIdx.x * 256 + tid;
  int v = (i < n) ? cnt[i] : 0;
  #pragma unroll
  for (int off = 32; off >= 1; off >>= 1) v += __shfl_xor(v, off, 64);
  if (lane == 0) wp[wid] = v;
  __syncthreads();
  if (tid == 0) bsum[blockIdx.x] = wp[0] + wp[1] + wp[2] + wp[3];
}

__global__ void bscan_kernel(int* __restrict__ bsum, int nb) {
  __shared__ int wp[4];
  int tid = threadIdx.x, lane = tid & 63, wid = tid >> 6;
  int v = (tid < nb) ? bsum[tid] : 0;
  int xv = v;
  #pragma unroll
  for (int off = 1; off < 64; off <<= 1) {
    int y = __shfl_up(xv, off, 64);
    if (lane >= off) xv += y;
  }
  if (lane == 63) wp[wid] = xv;
  __syncthreads();
  if (tid == 0) { int s = 0; for (int k = 0; k < 4; k++) { int t = wp[k]; wp[k] = s; s += t; } }
  __syncthreads();
  if (tid < nb) bsum[tid] = wp[wid] + xv - v;   // exclusive
}

__global__ void rpfill_kernel(const int* __restrict__ cnt, const int* __restrict__ bsum,
                              int* __restrict__ rp, int n, int E) {
  __shared__ int wp[4];
  int tid = threadIdx.x, lane = tid & 63, wid = tid >> 6;
  int i = blockIdx.x * 256 + tid;
  int v = (i < n) ? cnt[i] : 0;
  int xv = v;
  #pragma unroll
  for (int off = 1; off < 64; off <<= 1) {
    int y = __shfl_up(xv, off, 64);
    if (lane >= off) xv += y;
  }
  if (lane == 63) wp[wid] = xv;
  __syncthreads();
  if (tid == 0) { int s = 0; for (int k = 0; k < 4; k++) { int t = wp[k]; wp[k] = s; s += t; } }
  __syncthreads();
  if (i < n) rp[i] = bsum[blockIdx.x] + wp[wid] + xv - v;
  if (blockIdx.x == 0 && tid == 0) rp[n] = E;
}

__global__ void dinv_kernel(const int* __restrict__ cnt, float* __restrict__ dinv, int n) {
  int v = blockIdx.x * 256 + threadIdx.x;
  if (v < n) dinv[v] = rsqrtf((float)(cnt[v] + 1));
}

__global__ void fill_kernel(const int* __restrict__ src, const int* __restrict__ dst,
                            const int* __restrict__ rp, int* __restrict__ fil,
                            int* __restrict__ csr, int* __restrict__ csr_dst, int E) {
  int e = blockIdx.x * 256 + threadIdx.x;
  if (e < E) {
    int d = dst[e];
    int pos = rp[d] + atomicAdd(&fil[d], 1);
    csr[pos] = src[e];
    csr_dst[pos] = d;
  }
}

// ---------------- GCN aggregate (wave/node, chunked edge preload, bf16 h) --
__global__ void gcn_agg_kernel(const __bf16* __restrict__ h, const int* __restrict__ rp,
                               const int* __restrict__ csr, const float* __restrict__ dinv,
                               const float* __restrict__ bias, __bf16* __restrict__ out, int n)
{
  const int lane = threadIdx.x & 63;
  const int v = blockIdx.x * 4 + (threadIdx.x >> 6);
  if (v >= n) return;
  const float dv = dinv[v];
  const int e0 = rp[v], e1 = rp[v + 1];
  float acc[5];
  #pragma unroll
  for (int j = 0; j < 5; j++) acc[j] = dv * (float)h[(size_t)v * FDIM + lane + 64 * j];
  for (int base = e0; base < e1; base += 64) {
    int nn = min(64, e1 - base);
    int s_l = (lane < nn) ? csr[base + lane] : 0;
    float d_l = (lane < nn) ? dinv[s_l] : 0.f;
    for (int j2 = 0; j2 < nn; j2++) {
      int sj = __shfl(s_l, j2, 64);
      float cj = __shfl(d_l, j2, 64);
      const __bf16* hs = h + (size_t)sj * FDIM;
      #pragma unroll
      for (int j = 0; j < 5; j++) acc[j] += cj * (float)hs[lane + 64 * j];
    }
  }
  #pragma unroll
  for (int j = 0; j < 5; j++) {
    float rr = dv * acc[j] + bias[lane + 64 * j];
    out[(size_t)v * FDIM + lane + 64 * j] = (__bf16)fmaxf(rr, 0.f);
  }
}

// ---------------- GAT attention scores a_s, a_d (one wave per node) --------
__global__ void gat_scores_kernel(const __bf16* __restrict__ h, const float* __restrict__ att_s,
                                  const float* __restrict__ att_d, float* __restrict__ as_,
                                  float* __restrict__ ad_, int n)
{
  const int lane = threadIdx.x & 63;
  const int v = blockIdx.x * 4 + (threadIdx.x >> 6);
  if (v >= n) return;
  const int c = lane & 31;
  const int hh = lane >> 5;
  #pragma unroll
  for (int j = 0; j < 5; j++) {
    int head = hh * 5 + j;
    float xv = (float)h[(size_t)v * FDIM + head * 32 + c];
    float ps = xv * att_s[head * 32 + c];
    float pd = xv * att_d[head * 32 + c];
    #pragma unroll
    for (int off = 1; off < 32; off <<= 1) {
      ps += __shfl_xor(ps, off, 64);
      pd += __shfl_xor(pd, off, 64);
    }
    if (c == 0) { as_[v * NHEADS + head] = ps; ad_[v * NHEADS + head] = pd; }
  }
}

__device__ __forceinline__ float lrelu(float x) { return x > 0.f ? x : 0.2f * x; }

// ---------------- edge-parallel raw scores, PLANE layout es[t*E + e] -------
__global__ void escore_kernel(const int* __restrict__ csr, const int* __restrict__ csr_dst,
                              const float* __restrict__ as_, const float* __restrict__ ad_,
                              float* __restrict__ es, int E)
{
  int i = blockIdx.x * 256 + threadIdx.x;
  if (i >= E) return;
  int s = csr[i], d = csr_dst[i];
  const float* ap = as_ + (size_t)s * NHEADS;
  const float* dp = ad_ + (size_t)d * NHEADS;
  #pragma unroll
  for (int t = 0; t < NHEADS; t++) es[(size_t)t * E + i] = lrelu(ap[t] + dp[t]);
}

// ---------------- per-(node,head) segment max + denom; head = blockIdx.y ---
__global__ void mdenom_kernel(const float* __restrict__ es, const int* __restrict__ rp,
                              const float* __restrict__ as_, const float* __restrict__ ad_,
                              float* __restrict__ mseg, float* __restrict__ invden,
                              float* __restrict__ aself, int n, int E)
{
  int v = blockIdx.x * 256 + threadIdx.x;
  if (v >= n) return;
  int t = blockIdx.y;
  int e0 = rp[v], e1 = rp[v + 1];
  float esf = lrelu(as_[v * NHEADS + t] + ad_[v * NHEADS + t]);
  const float* ep = es + (size_t)t * E;
  float m = esf;
  for (int e = e0; e < e1; e++) m = fmaxf(m, ep[e]);
  float den = __expf(esf - m);
  float pself = den;
  for (int e = e0; e < e1; e++) den += __expf(ep[e] - m);
  float inv = 1.f / den;
  mseg[v * NHEADS + t] = m;
  invden[v * NHEADS + t] = inv;
  aself[v * NHEADS + t] = pself * inv;
}

// ---------------- edge-parallel alpha (in-place on es planes) --------------
__global__ void alpha_kernel(const int* __restrict__ csr_dst, const float* __restrict__ mseg,
                             const float* __restrict__ invden, float* __restrict__ es, int E)
{
  int i = blockIdx.x * 256 + threadIdx.x;
  if (i >= E) return;
  int d = csr_dst[i];
  const float* mp = mseg + (size_t)d * NHEADS;
  const float* ip = invden + (size_t)d * NHEADS;
  #pragma unroll
  for (int t = 0; t < NHEADS; t++) {
    size_t idx = (size_t)t * E + i;
    es[idx] = __expf(es[idx] - mp[t]) * ip[t];
  }
}

// ---------------- GAT aggregate (wave/node, chunked edge preload, bf16 h) --
__global__ void gat_agg_kernel(const __bf16* __restrict__ h, const int* __restrict__ rp,
                               const int* __restrict__ csr, const float* __restrict__ alpha,
                               const float* __restrict__ aself, const float* __restrict__ bias,
                               __bf16* __restrict__ out, int n, int E)
{
  const int lane = threadIdx.x & 63;
  const int v = blockIdx.x * 4 + (threadIdx.x >> 6);
  if (v >= n) return;
  const int hb = lane >> 5;   // head of channel lane+64j is 2j+hb
  const int e0 = rp[v], e1 = rp[v + 1];
  const float* asf = aself + (size_t)v * NHEADS;
  float acc[5];
  #pragma unroll
  for (int j = 0; j < 5; j++)
    acc[j] = asf[2 * j + hb] * (float)h[(size_t)v * FDIM + lane + 64 * j];
  for (int base = e0; base < e1; base += 64) {
    int nn = min(64, e1 - base);
    int s_l = (lane < nn) ? csr[base + lane] : 0;
    for (int j2 = 0; j2 < nn; j2++) {
      int sj = __shfl(s_l, j2, 64);
      const float* al = alpha + base + j2;
      const __bf16* hs = h + (size_t)sj * FDIM;
      #pragma unroll
      for (int j = 0; j < 5; j++)
        acc[j] += al[(size_t)(2 * j + hb) * E] * (float)hs[lane + 64 * j];
    }
  }
  #pragma unroll
  for (int j = 0; j < 5; j++) {
    int c = lane + 64 * j;
    float rr = acc[j] + bias[c];
    out[(size_t)v * FDIM + c] = (__bf16)fmaxf(rr, 0.f);
  }
}

// ---------------- batch boundaries + pooling ----------------
__global__ void bstart_kernel(const int* __restrict__ batch, int* __restrict__ bstart,
                              int n, int B_) {
  int v = blockIdx.x * 256 + threadIdx.x;
  if (v > n) return;
  int bv = (v < n) ? batch[v] : B_;
  int bp = (v == 0) ? -1 : batch[v - 1];
  for (int gg = bp + 1; gg <= bv; gg++) bstart[gg] = v;
}

__global__ void pool_kernel(const __bf16* __restrict__ xin, const int* __restrict__ bstart,
                            float* __restrict__ g) {
  int gid = blockIdx.x;
  int c = blockIdx.y * 64 + threadIdx.x;
  int s = bstart[gid], e = bstart[gid + 1];
  float mx = -__builtin_inff(), sm = 0.f;
  for (int v = s; v < e; v++) {
    float val = (float)xin[(size_t)v * FDIM + c];
    mx = fmaxf(mx, val);
    sm += val;
  }
  float cntf = (float)(e - s);
  g[gid * (2 * FDIM) + c] = mx;
  g[gid * (2 * FDIM) + FDIM + c] = sm / fmaxf(cntf, 1.f);
}

// ---------------- launch ----------------
extern "C" void kernel_launch(void* const* d_in, const int* in_sizes, int n_in,
                              void* d_out, int out_size, void* d_ws, size_t ws_size,
                              hipStream_t stream)
{
  const int N = in_sizes[0] / FDIM;
  const int E = in_sizes[2] / 2;
  const int NB = (N + 255) / 256;

  const float* x[2]   = {(const float*)d_in[0], (const float*)d_in[1]};
  const int*   ei[2]  = {(const int*)d_in[2], (const int*)d_in[3]};
  const int*   bat[2] = {(const int*)d_in[4], (const int*)d_in[5]};
  const float* W_gcn   = (const float*)d_in[6];
  const float* b_gcn   = (const float*)d_in[7];
  const float* W_gat   = (const float*)d_in[8];
  const float* att_src = (const float*)d_in[9];
  const float* att_dst = (const float*)d_in[10];
  const float* b_gat   = (const float*)d_in[11];
  const float* W_fc_g1 = (const float*)d_in[12];
  const float* b_fc_g1 = (const float*)d_in[13];
  const float* W_fc_g2 = (const float*)d_in[14];
  const float* b_fc_g2 = (const float*)d_in[15];
  const float* W_fc1   = (const float*)d_in[16];
  const float* b_fc1   = (const float*)d_in[17];
  const float* W_fc2   = (const float*)d_in[18];
  const float* b_fc2   = (const float*)d_in[19];
  const float* W_out   = (const float*)d_in[20];
  const float* b_out   = (const float*)d_in[21];
  float* outp = (float*)d_out;

  char* ws = (char*)d_ws;
  size_t off = 0;
  auto alloc = [&](size_t bytes) -> char* {
    char* p = ws + off;
    off += (bytes + 255) & ~(size_t)255;
    return p;
  };
  int*    cnt    = (int*)alloc((size_t)N * 4);
  int*    fil    = (int*)alloc((size_t)N * 4);
  int*    rp     = (int*)alloc((size_t)(N + 1) * 4);
  int*    bsum   = (int*)alloc((size_t)NB * 4);
  int*    csr    = (int*)alloc((size_t)E * 4);
  int*    csrd   = (int*)alloc((size_t)E * 4);
  float*  dinv   = (float*)alloc((size_t)N * 4);
  int*    bstart = (int*)alloc((size_t)(NGR + 1) * 4);
  __bf16* WgcnT  = (__bf16*)alloc((size_t)FDIM * FDIM * 2);
  __bf16* WgatT  = (__bf16*)alloc((size_t)FDIM * FDIM * 2);
  __bf16* hbuf   = (__bf16*)alloc((size_t)N * FDIM * 2);
  __bf16* xbuf   = (__bf16*)alloc((size_t)N * FDIM * 2);
  float*  as_    = (float*)alloc((size_t)N * NHEADS * 4);
  float*  ad_    = (float*)alloc((size_t)N * NHEADS * 4);
  float*  es     = (float*)alloc((size_t)E * NHEADS * 4);
  float*  mseg   = (float*)alloc((size_t)N * NHEADS * 4);
  float*  invden = (float*)alloc((size_t)N * NHEADS * 4);
  float*  aself  = (float*)alloc((size_t)N * NHEADS * 4);
  float*  g      = (float*)alloc((size_t)NGR * 2 * FDIM * 4);
  float*  t1     = (float*)alloc((size_t)NGR * 1500 * 4);
  float*  xc     = (float*)alloc((size_t)NGR * 256 * 4);
  float*  t2     = (float*)alloc((size_t)NGR * 1024 * 4);
  float*  t3     = (float*)alloc((size_t)NGR * 512 * 4);
  if (off > ws_size) return;  // workspace too small: bail (visible as absmax fail)

  wconv_kernel<<<(FDIM * FDIM) / 256, 256, 0, stream>>>(W_gcn, WgcnT);
  wconv_kernel<<<(FDIM * FDIM) / 256, 256, 0, stream>>>(W_gat, WgatT);

  for (int br = 0; br < 2; br++) {
    hipMemsetAsync(cnt, 0, (size_t)N * 4, stream);
    hipMemsetAsync(fil, 0, (size_t)N * 4, stream);
    const int* srcp = ei[br];
    const int* dstp = ei[br] + E;
    count_kernel<<<(E + 255) / 256, 256, 0, stream>>>(dstp, cnt, E);
    bsum_kernel<<<NB, 256, 0, stream>>>(cnt, bsum, N);
    bscan_kernel<<<1, 256, 0, stream>>>(bsum, NB);
    rpfill_kernel<<<NB, 256, 0, stream>>>(cnt, bsum, rp, N, E);
    dinv_kernel<<<(N + 255) / 256, 256, 0, stream>>>(cnt, dinv, N);
    fill_kernel<<<(E + 255) / 256, 256, 0, stream>>>(srcp, dstp, rp, fil, csr, csrd, E);

    int gemmblks = (N + 63) / 64;
    gemm320_kernel<float><<<gemmblks, 256, 0, stream>>>(x[br], WgcnT, hbuf, N);
    gcn_agg_kernel<<<(N + 3) / 4, 256, 0, stream>>>(hbuf, rp, csr, dinv, b_gcn, xbuf, N);
    gemm320_kernel<__bf16><<<gemmblks, 256, 0, stream>>>(xbuf, WgatT, hbuf, N);
    gat_scores_kernel<<<(N + 3) / 4, 256, 0, stream>>>(hbuf, att_src, att_dst, as_, ad_, N);

    escore_kernel<<<(E + 255) / 256, 256, 0, stream>>>(csr, csrd, as_, ad_, es, E);
    dim3 gmd(NB, NHEADS);
    mdenom_kernel<<<gmd, 256, 0, stream>>>(es, rp, as_, ad_, mseg, invden, aself, N, E);
    alpha_kernel<<<(E + 255) / 256, 256, 0, stream>>>(csrd, mseg, invden, es, E);
    gat_agg_kernel<<<(N + 3) / 4, 256, 0, stream>>>(hbuf, rp, csr, es, aself, b_gat, xbuf, N, E);

    bstart_kernel<<<(N + 256) / 256, 256, 0, stream>>>(bat[br], bstart, N, NGR);
    dim3 gpool(NGR, FDIM / 64);
    pool_kernel<<<gpool, 64, 0, stream>>>(xbuf, bstart, g);

    dim3 gfc1((NGR + BM - 1) / BM, (1500 + BN - 1) / BN);
    gemm_bf16_kernel<3><<<gfc1, 256, 0, stream>>>(g, W_fc_g1, t1, b_fc_g1, NGR, 1500, 2 * FDIM, 1500);
    dim3 gfc2((NGR + BM - 1) / BM, (128 + BN - 1) / BN);
    gemm_bf16_kernel<2><<<gfc2, 256, 0, stream>>>(t1, W_fc_g2, xc + br * 128, b_fc_g2, NGR, 128, 1500, 256);
  }

  dim3 gx1((NGR + BM - 1) / BM, (1024 + BN - 1) / BN);
  gemm_bf16_kernel<3><<<gx1, 256, 0, stream>>>(xc, W_fc1, t2, b_fc1, NGR, 1024, 256, 1024);
  dim3 gx2((NGR + BM - 1) / BM, (512 + BN - 1) / BN);
  gemm_bf16_kernel<3><<<gx2, 256, 0, stream>>>(t2, W_fc2, t3, b_fc2, NGR, 512, 1024, 512);
  dim3 gx3((NGR + BM - 1) / BM, 1);
  gemm_bf16_kernel<2><<<gx3, 256, 0, stream>>>(t3, W_out, outp, b_out, NGR, 2, 512, 2);
}

// Round 5
// 888.898 us; speedup vs baseline: 2.7627x; 1.2156x over previous
//
#include <hip/hip_runtime.h>
#include <type_traits>

#define FDIM 320
#define NHEADS 10
#define NGR 256

typedef __bf16 bf16x8 __attribute__((ext_vector_type(8)));
typedef float f32x4 __attribute__((ext_vector_type(4)));

// ---------------- weight transpose+convert: Wt[c*320+k] = (bf16)W[k*320+c] --
__global__ void wconv_kernel(const float* __restrict__ W, __bf16* __restrict__ Wt) {
  int idx = blockIdx.x * 256 + threadIdx.x;
  int k = idx / FDIM, c = idx - k * FDIM;
  Wt[c * FDIM + k] = (__bf16)W[idx];
}

// ---------------- node GEMM: C[M,320] = A[M,320] * W[320,320], full-N tile -
#define GLSTR 40

template<typename TA>
__global__ __launch_bounds__(256) void gemm320_kernel(
    const TA* __restrict__ A, const __bf16* __restrict__ Wt,
    __bf16* __restrict__ C, int M)
{
  __shared__ __bf16 As[64 * GLSTR];
  __shared__ __bf16 Bs[320 * GLSTR];

  const int tid = threadIdx.x;
  const int lane = tid & 63;
  const int w = tid >> 6;
  const int wr = w >> 1, wc = w & 1;
  const int r = lane & 15, kg = lane >> 4;
  const int m0 = blockIdx.x * 64;

  f32x4 acc0[10], acc1[10];
  #pragma unroll
  for (int i = 0; i < 10; i++) { acc0[i] = (f32x4){0,0,0,0}; acc1[i] = (f32x4){0,0,0,0}; }

  const int arow = tid >> 2, aq = tid & 3;

  for (int k0 = 0; k0 < 320; k0 += 32) {
    __syncthreads();
    {
      int gm = m0 + arow;
      bf16x8 v = {};
      if (gm < M) {
        if constexpr (std::is_same_v<TA, float>) {
          const float4* ap = (const float4*)(A + (size_t)gm * FDIM + k0 + aq * 8);
          float4 u0 = ap[0], u1 = ap[1];
          v[0]=(__bf16)u0.x; v[1]=(__bf16)u0.y; v[2]=(__bf16)u0.z; v[3]=(__bf16)u0.w;
          v[4]=(__bf16)u1.x; v[5]=(__bf16)u1.y; v[6]=(__bf16)u1.z; v[7]=(__bf16)u1.w;
        } else {
          v = *(const bf16x8*)(A + (size_t)gm * FDIM + k0 + aq * 8);
        }
      }
      *(bf16x8*)&As[arow * GLSTR + aq * 8] = v;
    }
    {
      const bf16x8* sp = (const bf16x8*)(Wt + (size_t)tid * FDIM + k0);
      bf16x8 b0 = sp[0], b1 = sp[1], b2 = sp[2], b3 = sp[3];
      bf16x8* dp = (bf16x8*)&Bs[tid * GLSTR];
      dp[0] = b0; dp[1] = b1; dp[2] = b2; dp[3] = b3;
      if (tid < 64) {
        int c2 = 256 + tid;
        const bf16x8* sp2 = (const bf16x8*)(Wt + (size_t)c2 * FDIM + k0);
        bf16x8 c0 = sp2[0], c1 = sp2[1], c22 = sp2[2], c3 = sp2[3];
        bf16x8* dp2 = (bf16x8*)&Bs[c2 * GLSTR];
        dp2[0] = c0; dp2[1] = c1; dp2[2] = c22; dp2[3] = c3;
      }
    }
    __syncthreads();
    bf16x8 af0 = *(const bf16x8*)&As[(wr*32 + 0  + r) * GLSTR + kg*8];
    bf16x8 af1 = *(const bf16x8*)&As[(wr*32 + 16 + r) * GLSTR + kg*8];
    #pragma unroll
    for (int nf = 0; nf < 10; nf++) {
      bf16x8 bfr = *(const bf16x8*)&Bs[(wc*160 + nf*16 + r) * GLSTR + kg*8];
      acc0[nf] = __builtin_amdgcn_mfma_f32_16x16x32_bf16(af0, bfr, acc0[nf], 0, 0, 0);
      acc1[nf] = __builtin_amdgcn_mfma_f32_16x16x32_bf16(af1, bfr, acc1[nf], 0, 0, 0);
    }
  }

  #pragma unroll
  for (int nf = 0; nf < 10; nf++) {
    int gn = wc*160 + nf*16 + r;
    #pragma unroll
    for (int q = 0; q < 4; q++) {
      int gm0 = m0 + wr*32 + kg*4 + q;
      if (gm0 < M)      C[(size_t)gm0 * FDIM + gn] = (__bf16)acc0[nf][q];
      int gm1 = gm0 + 16;
      if (gm1 < M)      C[(size_t)gm1 * FDIM + gn] = (__bf16)acc1[nf][q];
    }
  }
}

// ---------------- generic GEMM (FC layers): C = A*B, f32 in/out ------------
#define BM 128
#define BN 64
#define BK 32
#define LSTR 56

template<int FLAGS>  // bit0: relu, bit1: bias
__global__ __launch_bounds__(256) void gemm_bf16_kernel(
    const float* __restrict__ A, const float* __restrict__ B,
    float* __restrict__ C, const float* __restrict__ bias,
    int M, int N, int K, int ldc)
{
  __shared__ __bf16 As[BM * LSTR];
  __shared__ __bf16 Bs[BN * LSTR];

  const int tid = threadIdx.x;
  const int lane = tid & 63;
  const int w = tid >> 6;
  const int wm = w >> 1, wn = w & 1;
  const int r = lane & 15, kg = lane >> 4;
  const int m0 = blockIdx.x * BM, n0 = blockIdx.y * BN;

  f32x4 acc[4][2];
  #pragma unroll
  for (int i = 0; i < 4; i++)
    #pragma unroll
    for (int j = 0; j < 2; j++)
      acc[i][j] = (f32x4){0.f, 0.f, 0.f, 0.f};

  const int arow = tid >> 1, ahalf = tid & 1;
  const int bk = tid >> 3, bn = (tid & 7) * 8;

  for (int k0 = 0; k0 < K; k0 += BK) {
    __syncthreads();
    {
      int gm = m0 + arow;
      int kbase = k0 + ahalf * 16;
      float tmp[16];
      if (gm < M && kbase + 16 <= K) {
        const float4* ap = (const float4*)(A + (size_t)gm * K + kbase);
        #pragma unroll
        for (int q = 0; q < 4; q++) {
          float4 v = ap[q];
          tmp[q*4+0] = v.x; tmp[q*4+1] = v.y; tmp[q*4+2] = v.z; tmp[q*4+3] = v.w;
        }
      } else {
        #pragma unroll
        for (int q = 0; q < 16; q++) {
          int kk = kbase + q;
          tmp[q] = (gm < M && kk < K) ? A[(size_t)gm * K + kk] : 0.f;
        }
      }
      bf16x8 v0, v1;
      #pragma unroll
      for (int q = 0; q < 8; q++) { v0[q] = (__bf16)tmp[q]; v1[q] = (__bf16)tmp[q+8]; }
      bf16x8* dp = (bf16x8*)&As[arow * LSTR + ahalf * 16];
      dp[0] = v0; dp[1] = v1;
    }
    {
      int gk = k0 + bk;
      float tb[8];
      if (gk < K && n0 + bn + 8 <= N) {
        const float4* bp = (const float4*)(B + (size_t)gk * N + n0 + bn);
        float4 u0 = bp[0], u1 = bp[1];
        tb[0]=u0.x; tb[1]=u0.y; tb[2]=u0.z; tb[3]=u0.w;
        tb[4]=u1.x; tb[5]=u1.y; tb[6]=u1.z; tb[7]=u1.w;
      } else {
        #pragma unroll
        for (int q = 0; q < 8; q++) {
          int gn = n0 + bn + q;
          tb[q] = (gk < K && gn < N) ? B[(size_t)gk * N + gn] : 0.f;
        }
      }
      #pragma unroll
      for (int q = 0; q < 8; q++) Bs[(bn + q) * LSTR + bk] = (__bf16)tb[q];
    }
    __syncthreads();
    bf16x8 af[4], bfr[2];
    #pragma unroll
    for (int mf = 0; mf < 4; mf++)
      af[mf] = *(const bf16x8*)&As[(wm*64 + mf*16 + r) * LSTR + kg*8];
    #pragma unroll
    for (int nf = 0; nf < 2; nf++)
      bfr[nf] = *(const bf16x8*)&Bs[(wn*32 + nf*16 + r) * LSTR + kg*8];
    #pragma unroll
    for (int mf = 0; mf < 4; mf++)
      #pragma unroll
      for (int nf = 0; nf < 2; nf++)
        acc[mf][nf] = __builtin_amdgcn_mfma_f32_16x16x32_bf16(af[mf], bfr[nf], acc[mf][nf], 0, 0, 0);
  }

  #pragma unroll
  for (int mf = 0; mf < 4; mf++) {
    #pragma unroll
    for (int nf = 0; nf < 2; nf++) {
      #pragma unroll
      for (int q = 0; q < 4; q++) {
        int gm = m0 + wm*64 + mf*16 + kg*4 + q;
        int gn = n0 + wn*32 + nf*16 + r;
        if (gm < M && gn < N) {
          float v = acc[mf][nf][q];
          if (FLAGS & 2) v += bias[gn];
          if (FLAGS & 1) v = fmaxf(v, 0.f);
          C[(size_t)gm * ldc + gn] = v;
        }
      }
    }
  }
}

// ---------------- split-K GEMM: P[s][M][N] partials ----------------
__global__ __launch_bounds__(256) void gemm_splitk_kernel(
    const float* __restrict__ A, const float* __restrict__ B,
    float* __restrict__ P, int M, int N, int K, int KS)
{
  __shared__ __bf16 As[BM * LSTR];
  __shared__ __bf16 Bs[BN * LSTR];

  const int tid = threadIdx.x;
  const int lane = tid & 63;
  const int w = tid >> 6;
  const int wm = w >> 1, wn = w & 1;
  const int r = lane & 15, kg = lane >> 4;
  const int m0 = blockIdx.x * BM, n0 = blockIdx.y * BN;
  const int kstart = blockIdx.z * KS;
  const int kend = min(K, kstart + KS);

  f32x4 acc[4][2];
  #pragma unroll
  for (int i = 0; i < 4; i++)
    #pragma unroll
    for (int j = 0; j < 2; j++)
      acc[i][j] = (f32x4){0.f, 0.f, 0.f, 0.f};

  const int arow = tid >> 1, ahalf = tid & 1;
  const int bk = tid >> 3, bn = (tid & 7) * 8;

  for (int k0 = kstart; k0 < kend; k0 += BK) {
    __syncthreads();
    {
      int gm = m0 + arow;
      int kbase = k0 + ahalf * 16;
      float tmp[16];
      if (gm < M && kbase + 16 <= kend) {
        const float4* ap = (const float4*)(A + (size_t)gm * K + kbase);
        #pragma unroll
        for (int q = 0; q < 4; q++) {
          float4 v = ap[q];
          tmp[q*4+0] = v.x; tmp[q*4+1] = v.y; tmp[q*4+2] = v.z; tmp[q*4+3] = v.w;
        }
      } else {
        #pragma unroll
        for (int q = 0; q < 16; q++) {
          int kk = kbase + q;
          tmp[q] = (gm < M && kk < kend) ? A[(size_t)gm * K + kk] : 0.f;
        }
      }
      bf16x8 v0, v1;
      #pragma unroll
      for (int q = 0; q < 8; q++) { v0[q] = (__bf16)tmp[q]; v1[q] = (__bf16)tmp[q+8]; }
      bf16x8* dp = (bf16x8*)&As[arow * LSTR + ahalf * 16];
      dp[0] = v0; dp[1] = v1;
    }
    {
      int gk = k0 + bk;
      float tb[8];
      if (gk < kend && n0 + bn + 8 <= N) {
        const float4* bp = (const float4*)(B + (size_t)gk * N + n0 + bn);
        float4 u0 = bp[0], u1 = bp[1];
        tb[0]=u0.x; tb[1]=u0.y; tb[2]=u0.z; tb[3]=u0.w;
        tb[4]=u1.x; tb[5]=u1.y; tb[6]=u1.z; tb[7]=u1.w;
      } else {
        #pragma unroll
        for (int q = 0; q < 8; q++) {
          int gn = n0 + bn + q;
          tb[q] = (gk < kend && gn < N) ? B[(size_t)gk * N + gn] : 0.f;
        }
      }
      #pragma unroll
      for (int q = 0; q < 8; q++) Bs[(bn + q) * LSTR + bk] = (__bf16)tb[q];
    }
    __syncthreads();
    bf16x8 af[4], bfr[2];
    #pragma unroll
    for (int mf = 0; mf < 4; mf++)
      af[mf] = *(const bf16x8*)&As[(wm*64 + mf*16 + r) * LSTR + kg*8];
    #pragma unroll
    for (int nf = 0; nf < 2; nf++)
      bfr[nf] = *(const bf16x8*)&Bs[(wn*32 + nf*16 + r) * LSTR + kg*8];
    #pragma unroll
    for (int mf = 0; mf < 4; mf++)
      #pragma unroll
      for (int nf = 0; nf < 2; nf++)
        acc[mf][nf] = __builtin_amdgcn_mfma_f32_16x16x32_bf16(af[mf], bfr[nf], acc[mf][nf], 0, 0, 0);
  }

  float* Pp = P + (size_t)blockIdx.z * M * N;
  #pragma unroll
  for (int mf = 0; mf < 4; mf++) {
    #pragma unroll
    for (int nf = 0; nf < 2; nf++) {
      #pragma unroll
      for (int q = 0; q < 4; q++) {
        int gm = m0 + wm*64 + mf*16 + kg*4 + q;
        int gn = n0 + wn*32 + nf*16 + r;
        if (gm < M && gn < N)
          Pp[(size_t)gm * N + gn] = acc[mf][nf][q];
      }
    }
  }
}

// reduce partials; STACK: rows M/2.. go to cols N.. (fc_g2 branch packing)
template<int FLAGS, bool STACK>
__global__ void reduce_kernel(const float* __restrict__ P, float* __restrict__ C,
                              const float* __restrict__ bias, int M, int N, int S, int ldc)
{
  int i = blockIdx.x * 256 + threadIdx.x;
  if (i >= M * N) return;
  float v = 0.f;
  for (int s = 0; s < S; s++) v += P[(size_t)s * M * N + i];
  int row = i / N, col = i - row * N;
  if (FLAGS & 2) v += bias[col];
  if (FLAGS & 1) v = fmaxf(v, 0.f);
  if (STACK) { if (row >= (M >> 1)) { row -= (M >> 1); col += N; } }
  C[(size_t)row * ldc + col] = v;
}

// ---------------- CSR build ----------------
__global__ void count_kernel(const int* __restrict__ dst, int* __restrict__ cnt, int E) {
  int e = blockIdx.x * 256 + threadIdx.x;
  if (e < E) atomicAdd(&cnt[dst[e]], 1);
}

__global__ void bsum_kernel(const int* __restrict__ cnt, int* __restrict__ bsum, int n) {
  __shared__ int wp[4];
  int tid = threadIdx.x, lane = tid & 63, wid = tid >> 6;
  int i = blockIdx.x * 256 + tid;
  int v = (i < n) ? cnt[i] : 0;
  #pragma unroll
  for (int off = 32; off >= 1; off >>= 1) v += __shfl_xor(v, off, 64);
  if (lane == 0) wp[wid] = v;
  __syncthreads();
  if (tid == 0) bsum[blockIdx.x] = wp[0] + wp[1] + wp[2] + wp[3];
}

__global__ void bscan_kernel(int* __restrict__ bsum, int nb) {
  __shared__ int wp[4];
  int tid = threadIdx.x, lane = tid & 63, wid = tid >> 6;
  int v = (tid < nb) ? bsum[tid] : 0;
  int xv = v;
  #pragma unroll
  for (int off = 1; off < 64; off <<= 1) {
    int y = __shfl_up(xv, off, 64);
    if (lane >= off) xv += y;
  }
  if (lane == 63) wp[wid] = xv;
  __syncthreads();
  if (tid == 0) { int s = 0; for (int k = 0; k < 4; k++) { int t = wp[k]; wp[k] = s; s += t; } }
  __syncthreads();
  if (tid < nb) bsum[tid] = wp[wid] + xv - v;   // exclusive
}

__global__ void rpfill_kernel(const int* __restrict__ cnt, const int* __restrict__ bsum,
                              int* __restrict__ rp, float* __restrict__ dinv, int n, int E) {
  __shared__ int wp[4];
  int tid = threadIdx.x, lane = tid & 63, wid = tid >> 6;
  int i = blockIdx.x * 256 + tid;
  int v = (i < n) ? cnt[i] : 0;
  int xv = v;
  #pragma unroll
  for (int off = 1; off < 64; off <<= 1) {
    int y = __shfl_up(xv, off, 64);
    if (lane >= off) xv += y;
  }
  if (lane == 63) wp[wid] = xv;
  __syncthreads();
  if (tid == 0) { int s = 0; for (int k = 0; k < 4; k++) { int t = wp[k]; wp[k] = s; s += t; } }
  __syncthreads();
  if (i < n) {
    rp[i] = bsum[blockIdx.x] + wp[wid] + xv - v;
    dinv[i] = rsqrtf((float)(v + 1));
  }
  if (blockIdx.x == 0 && tid == 0) rp[n] = E;
}

__global__ void fill_kernel(const int* __restrict__ src, const int* __restrict__ dst,
                            const int* __restrict__ rp, int* __restrict__ fil,
                            int* __restrict__ csr, int* __restrict__ csr_dst, int E) {
  int e = blockIdx.x * 256 + threadIdx.x;
  if (e < E) {
    int d = dst[e];
    int pos = rp[d] + atomicAdd(&fil[d], 1);
    csr[pos] = src[e];
    csr_dst[pos] = d;
  }
}

// ---------------- GCN aggregate (wave/node, chunked edge preload, bf16 h) --
__global__ void gcn_agg_kernel(const __bf16* __restrict__ h, const int* __restrict__ rp,
                               const int* __restrict__ csr, const float* __restrict__ dinv,
                               const float* __restrict__ bias, __bf16* __restrict__ out, int n)
{
  const int lane = threadIdx.x & 63;
  const int v = blockIdx.x * 4 + (threadIdx.x >> 6);
  if (v >= n) return;
  const float dv = dinv[v];
  const int e0 = rp[v], e1 = rp[v + 1];
  float acc[5];
  #pragma unroll
  for (int j = 0; j < 5; j++) acc[j] = dv * (float)h[(size_t)v * FDIM + lane + 64 * j];
  for (int base = e0; base < e1; base += 64) {
    int nn = min(64, e1 - base);
    int s_l = (lane < nn) ? csr[base + lane] : 0;
    float d_l = (lane < nn) ? dinv[s_l] : 0.f;
    for (int j2 = 0; j2 < nn; j2++) {
      int sj = __shfl(s_l, j2, 64);
      float cj = __shfl(d_l, j2, 64);
      const __bf16* hs = h + (size_t)sj * FDIM;
      #pragma unroll
      for (int j = 0; j < 5; j++) acc[j] += cj * (float)hs[lane + 64 * j];
    }
  }
  #pragma unroll
  for (int j = 0; j < 5; j++) {
    float rr = dv * acc[j] + bias[lane + 64 * j];
    out[(size_t)v * FDIM + lane + 64 * j] = (__bf16)fmaxf(rr, 0.f);
  }
}

// ---------------- GAT attention scores a_s, a_d (one wave per node) --------
__global__ void gat_scores_kernel(const __bf16* __restrict__ h, const float* __restrict__ att_s,
                                  const float* __restrict__ att_d, float* __restrict__ as_,
                                  float* __restrict__ ad_, int n)
{
  const int lane = threadIdx.x & 63;
  const int v = blockIdx.x * 4 + (threadIdx.x >> 6);
  if (v >= n) return;
  const int c = lane & 31;
  const int hh = lane >> 5;
  #pragma unroll
  for (int j = 0; j < 5; j++) {
    int head = hh * 5 + j;
    float xv = (float)h[(size_t)v * FDIM + head * 32 + c];
    float ps = xv * att_s[head * 32 + c];
    float pd = xv * att_d[head * 32 + c];
    #pragma unroll
    for (int off = 1; off < 32; off <<= 1) {
      ps += __shfl_xor(ps, off, 64);
      pd += __shfl_xor(pd, off, 64);
    }
    if (c == 0) { as_[v * NHEADS + head] = ps; ad_[v * NHEADS + head] = pd; }
  }
}

__device__ __forceinline__ float lrelu(float x) { return x > 0.f ? x : 0.2f * x; }

// ---------------- edge-parallel raw scores, PLANE layout es[t*E + e] -------
__global__ void escore_kernel(const int* __restrict__ csr, const int* __restrict__ csr_dst,
                              const float* __restrict__ as_, const float* __restrict__ ad_,
                              float* __restrict__ es, int E)
{
  int i = blockIdx.x * 256 + threadIdx.x;
  if (i >= E) return;
  int s = csr[i], d = csr_dst[i];
  const float* ap = as_ + (size_t)s * NHEADS;
  const float* dp = ad_ + (size_t)d * NHEADS;
  #pragma unroll
  for (int t = 0; t < NHEADS; t++) es[(size_t)t * E + i] = lrelu(ap[t] + dp[t]);
}

// ---------------- per-(node,head) segment max + denom; head = blockIdx.y ---
__global__ void mdenom_kernel(const float* __restrict__ es, const int* __restrict__ rp,
                              const float* __restrict__ as_, const float* __restrict__ ad_,
                              float* __restrict__ mseg, float* __restrict__ invden,
                              float* __restrict__ aself, int n, int E)
{
  int v = blockIdx.x * 256 + threadIdx.x;
  if (v >= n) return;
  int t = blockIdx.y;
  int e0 = rp[v], e1 = rp[v + 1];
  float esf = lrelu(as_[v * NHEADS + t] + ad_[v * NHEADS + t]);
  const float* ep = es + (size_t)t * E;
  float m = esf;
  for (int e = e0; e < e1; e++) m = fmaxf(m, ep[e]);
  float den = __expf(esf - m);
  float pself = den;
  for (int e = e0; e < e1; e++) den += __expf(ep[e] - m);
  float inv = 1.f / den;
  mseg[v * NHEADS + t] = m;
  invden[v * NHEADS + t] = inv;
  aself[v * NHEADS + t] = pself * inv;
}

// ---------------- edge-parallel alpha: planes -> interleaved [e][10] -------
__global__ void alpha_kernel(const int* __restrict__ csr_dst, const float* __restrict__ mseg,
                             const float* __restrict__ invden, const float* __restrict__ es,
                             float* __restrict__ aint, int E)
{
  int i = blockIdx.x * 256 + threadIdx.x;
  if (i >= E) return;
  int d = csr_dst[i];
  const float* mp = mseg + (size_t)d * NHEADS;
  const float* ip = invden + (size_t)d * NHEADS;
  float* op = aint + (size_t)i * NHEADS;
  #pragma unroll
  for (int t = 0; t < NHEADS; t++)
    op[t] = __expf(es[(size_t)t * E + i] - mp[t]) * ip[t];
}

// ---------------- GAT aggregate (wave/node, interleaved alpha, bf16 h) -----
__global__ void gat_agg_kernel(const __bf16* __restrict__ h, const int* __restrict__ rp,
                               const int* __restrict__ csr, const float* __restrict__ aint,
                               const float* __restrict__ aself, const float* __restrict__ bias,
                               __bf16* __restrict__ out, int n)
{
  const int lane = threadIdx.x & 63;
  const int v = blockIdx.x * 4 + (threadIdx.x >> 6);
  if (v >= n) return;
  const int hb = lane >> 5;   // head of channel lane+64j is 2j+hb
  const int e0 = rp[v], e1 = rp[v + 1];
  const float* asf = aself + (size_t)v * NHEADS;
  float acc[5];
  #pragma unroll
  for (int j = 0; j < 5; j++)
    acc[j] = asf[2 * j + hb] * (float)h[(size_t)v * FDIM + lane + 64 * j];
  for (int base = e0; base < e1; base += 64) {
    int nn = min(64, e1 - base);
    int s_l = (lane < nn) ? csr[base + lane] : 0;
    for (int j2 = 0; j2 < nn; j2++) {
      int sj = __shfl(s_l, j2, 64);
      const float* al = aint + (size_t)(base + j2) * NHEADS;
      const __bf16* hs = h + (size_t)sj * FDIM;
      #pragma unroll
      for (int j = 0; j < 5; j++)
        acc[j] += al[2 * j + hb] * (float)hs[lane + 64 * j];
    }
  }
  #pragma unroll
  for (int j = 0; j < 5; j++) {
    int c = lane + 64 * j;
    float rr = acc[j] + bias[c];
    out[(size_t)v * FDIM + c] = (__bf16)fmaxf(rr, 0.f);
  }
}

// ---------------- batch boundaries + pooling ----------------
__global__ void bstart_kernel(const int* __restrict__ batch, int* __restrict__ bstart,
                              int n, int B_) {
  int v = blockIdx.x * 256 + threadIdx.x;
  if (v > n) return;
  int bv = (v < n) ? batch[v] : B_;
  int bp = (v == 0) ? -1 : batch[v - 1];
  for (int gg = bp + 1; gg <= bv; gg++) bstart[gg] = v;
}

__global__ void pool_kernel(const __bf16* __restrict__ xin, const int* __restrict__ bstart,
                            float* __restrict__ g) {
  int gid = blockIdx.x;
  int c = blockIdx.y * 64 + threadIdx.x;
  int s = bstart[gid], e = bstart[gid + 1];
  float mx = -__builtin_inff(), sm = 0.f;
  for (int v = s; v < e; v++) {
    float val = (float)xin[(size_t)v * FDIM + c];
    mx = fmaxf(mx, val);
    sm += val;
  }
  float cntf = (float)(e - s);
  g[gid * (2 * FDIM) + c] = mx;
  g[gid * (2 * FDIM) + FDIM + c] = sm / fmaxf(cntf, 1.f);
}

// ---------------- launch ----------------
extern "C" void kernel_launch(void* const* d_in, const int* in_sizes, int n_in,
                              void* d_out, int out_size, void* d_ws, size_t ws_size,
                              hipStream_t stream)
{
  const int N = in_sizes[0] / FDIM;
  const int E = in_sizes[2] / 2;
  const int NB = (N + 255) / 256;

  const float* x[2]   = {(const float*)d_in[0], (const float*)d_in[1]};
  const int*   ei[2]  = {(const int*)d_in[2], (const int*)d_in[3]};
  const int*   bat[2] = {(const int*)d_in[4], (const int*)d_in[5]};
  const float* W_gcn   = (const float*)d_in[6];
  const float* b_gcn   = (const float*)d_in[7];
  const float* W_gat   = (const float*)d_in[8];
  const float* att_src = (const float*)d_in[9];
  const float* att_dst = (const float*)d_in[10];
  const float* b_gat   = (const float*)d_in[11];
  const float* W_fc_g1 = (const float*)d_in[12];
  const float* b_fc_g1 = (const float*)d_in[13];
  const float* W_fc_g2 = (const float*)d_in[14];
  const float* b_fc_g2 = (const float*)d_in[15];
  const float* W_fc1   = (const float*)d_in[16];
  const float* b_fc1   = (const float*)d_in[17];
  const float* W_fc2   = (const float*)d_in[18];
  const float* b_fc2   = (const float*)d_in[19];
  const float* W_out   = (const float*)d_in[20];
  const float* b_out   = (const float*)d_in[21];
  float* outp = (float*)d_out;

  char* ws = (char*)d_ws;
  size_t off = 0;
  auto alloc = [&](size_t bytes) -> char* {
    char* p = ws + off;
    off += (bytes + 255) & ~(size_t)255;
    return p;
  };
  int*    cnt    = (int*)alloc((size_t)N * 4);
  int*    fil    = (int*)alloc((size_t)N * 4);
  size_t  zero_span = (size_t)((char*)fil - (char*)cnt) + ((size_t)N * 4 + 255 & ~(size_t)255);
  int*    rp     = (int*)alloc((size_t)(N + 1) * 4);
  int*    bsum   = (int*)alloc((size_t)NB * 4);
  int*    csr    = (int*)alloc((size_t)E * 4);
  int*    csrd   = (int*)alloc((size_t)E * 4);
  float*  dinv   = (float*)alloc((size_t)N * 4);
  int*    bstart = (int*)alloc((size_t)(NGR + 1) * 4);
  __bf16* WgcnT  = (__bf16*)alloc((size_t)FDIM * FDIM * 2);
  __bf16* WgatT  = (__bf16*)alloc((size_t)FDIM * FDIM * 2);
  __bf16* hbuf   = (__bf16*)alloc((size_t)N * FDIM * 2);
  __bf16* xbuf   = (__bf16*)alloc((size_t)N * FDIM * 2);
  float*  as_    = (float*)alloc((size_t)N * NHEADS * 4);
  float*  ad_    = (float*)alloc((size_t)N * NHEADS * 4);
  float*  es     = (float*)alloc((size_t)E * NHEADS * 4);
  float*  aint   = (float*)alloc((size_t)E * NHEADS * 4);
  float*  mseg   = (float*)alloc((size_t)N * NHEADS * 4);
  float*  invden = (float*)alloc((size_t)N * NHEADS * 4);
  float*  aself  = (float*)alloc((size_t)N * NHEADS * 4);
  float*  g      = (float*)alloc((size_t)2 * NGR * 2 * FDIM * 4);   // both branches
  float*  t1     = (float*)alloc((size_t)2 * NGR * 1500 * 4);       // both branches
  float*  xc     = (float*)alloc((size_t)NGR * 256 * 4);
  float*  t2     = (float*)alloc((size_t)NGR * 1024 * 4);
  float*  t3     = (float*)alloc((size_t)NGR * 512 * 4);
  float*  part   = (float*)alloc((size_t)8 * 512 * 512 * 4);        // split-K partials (8 MB)
  if (off > ws_size) return;  // workspace too small: bail (visible as absmax fail)

  wconv_kernel<<<(FDIM * FDIM) / 256, 256, 0, stream>>>(W_gcn, WgcnT);
  wconv_kernel<<<(FDIM * FDIM) / 256, 256, 0, stream>>>(W_gat, WgatT);

  for (int br = 0; br < 2; br++) {
    hipMemsetAsync(cnt, 0, zero_span, stream);
    const int* srcp = ei[br];
    const int* dstp = ei[br] + E;
    count_kernel<<<(E + 255) / 256, 256, 0, stream>>>(dstp, cnt, E);
    bsum_kernel<<<NB, 256, 0, stream>>>(cnt, bsum, N);
    bscan_kernel<<<1, 256, 0, stream>>>(bsum, NB);
    rpfill_kernel<<<NB, 256, 0, stream>>>(cnt, bsum, rp, dinv, N, E);
    fill_kernel<<<(E + 255) / 256, 256, 0, stream>>>(srcp, dstp, rp, fil, csr, csrd, E);

    int gemmblks = (N + 63) / 64;
    gemm320_kernel<float><<<gemmblks, 256, 0, stream>>>(x[br], WgcnT, hbuf, N);
    gcn_agg_kernel<<<(N + 3) / 4, 256, 0, stream>>>(hbuf, rp, csr, dinv, b_gcn, xbuf, N);
    gemm320_kernel<__bf16><<<gemmblks, 256, 0, stream>>>(xbuf, WgatT, hbuf, N);
    gat_scores_kernel<<<(N + 3) / 4, 256, 0, stream>>>(hbuf, att_src, att_dst, as_, ad_, N);

    escore_kernel<<<(E + 255) / 256, 256, 0, stream>>>(csr, csrd, as_, ad_, es, E);
    dim3 gmd(NB, NHEADS);
    mdenom_kernel<<<gmd, 256, 0, stream>>>(es, rp, as_, ad_, mseg, invden, aself, N, E);
    alpha_kernel<<<(E + 255) / 256, 256, 0, stream>>>(csrd, mseg, invden, es, aint, E);
    gat_agg_kernel<<<(N + 3) / 4, 256, 0, stream>>>(hbuf, rp, csr, aint, aself, b_gat, xbuf, N);

    bstart_kernel<<<(N + 256) / 256, 256, 0, stream>>>(bat[br], bstart, N, NGR);
    dim3 gpool(NGR, FDIM / 64);
    pool_kernel<<<gpool, 64, 0, stream>>>(xbuf, bstart, g + (size_t)br * NGR * 2 * FDIM);
  }

  // ---- batched FC head: M=512 covers both branches ----
  {
    // fc_g1: [512, 640] x [640, 1500] -> t1 [512, 1500], bias+relu
    dim3 gfc1((512 + BM - 1) / BM, (1500 + BN - 1) / BN);
    gemm_bf16_kernel<3><<<gfc1, 256, 0, stream>>>(g, W_fc_g1, t1, b_fc_g1, 512, 1500, 2 * FDIM, 1500);
    // fc_g2: [512, 1500] x [1500, 128] -> xc packed [256, 256] via STACK
    int S = 8, KS = ((1500 + S * BK - 1) / (S * BK)) * BK;
    dim3 gfc2((512 + BM - 1) / BM, (128 + BN - 1) / BN, S);
    gemm_splitk_kernel<<<gfc2, 256, 0, stream>>>(t1, W_fc_g2, part, 512, 128, 1500, KS);
    reduce_kernel<2, true><<<(512 * 128 + 255) / 256, 256, 0, stream>>>(part, xc, b_fc_g2, 512, 128, S, 256);
  }
  {
    // fc1: [256,256] x [256,1024] -> t2, bias+relu
    dim3 gx1((NGR + BM - 1) / BM, (1024 + BN - 1) / BN);
    gemm_bf16_kernel<3><<<gx1, 256, 0, stream>>>(xc, W_fc1, t2, b_fc1, NGR, 1024, 256, 1024);
    // fc2: [256,1024] x [1024,512] -> t3, split-K S=4
    int S = 4, KS = ((1024 + S * BK - 1) / (S * BK)) * BK;
    dim3 gx2((NGR + BM - 1) / BM, (512 + BN - 1) / BN, S);
    gemm_splitk_kernel<<<gx2, 256, 0, stream>>>(t2, W_fc2, part, NGR, 512, 1024, KS);
    reduce_kernel<3, false><<<(NGR * 512 + 255) / 256, 256, 0, stream>>>(part, t3, b_fc2, NGR, 512, S, 512);
    // out: [256,512] x [512,2] -> outp, split-K S=4
    int S2 = 4, KS2 = ((512 + S2 * BK - 1) / (S2 * BK)) * BK;
    dim3 gx3((NGR + BM - 1) / BM, 1, S2);
    gemm_splitk_kernel<<<gx3, 256, 0, stream>>>(t3, W_out, part, NGR, 2, 512, KS2);
    reduce_kernel<2, false><<<(NGR * 2 + 255) / 256, 256, 0, stream>>>(part, outp, b_out, NGR, 2, S2, 2);
  }
}